// Round 3
// baseline (2208.977 us; speedup 1.0000x reference)
//
#include <hip/hip_runtime.h>
#include <hip/hip_bf16.h>

#define BQ 8192
#define CHUNK 2048
#define NCHUNK 4
typedef __attribute__((ext_vector_type(8))) __bf16 bf16x8;
typedef __attribute__((ext_vector_type(4))) float f32x4;
typedef __attribute__((ext_vector_type(4))) int int4v;

__device__ __forceinline__ f32x4 mfma16(bf16x8 a, bf16x8 b, f32x4 c) {
    return __builtin_amdgcn_mfma_f32_16x16x32_bf16(a, b, c, 0, 0, 0);
}

// 3-way bf16 split of an fp32 value: v ~= s0+s1+s2 to ~2^-25 rel.
__device__ __forceinline__ void split3(float v, __hip_bfloat16& s0,
                                       __hip_bfloat16& s1, __hip_bfloat16& s2) {
    s0 = __float2bfloat16(v);
    float r = v - __bfloat162float(s0);
    s1 = __float2bfloat16(r);
    r -= __bfloat162float(s1);
    s2 = __float2bfloat16(r);
}

// plane-pair schedule for 6-term fp32-emulated product (fc_partial still uses
// pair indexing): (a,w) = (0,0),(0,1),(0,2),(1,0),(1,1),(2,0)
// == A-plane ap paired with W-planes 0..(2-ap). conv_gemm exploits the grouped
// form directly (one A-read amortized over all paired W-planes).
__device__ __forceinline__ int pair_a(int pp) { return (0x211000 >> (4 * pp)) & 0xF; }
__device__ __forceinline__ int pair_w(int pp) { return (0x010210 >> (4 * pp)) & 0xF; }

// ---------------- prep kernels ----------------

__global__ void prep_scalars_k(
    const float* __restrict__ c1b, const float* __restrict__ g1,
    const float* __restrict__ b1,  const float* __restrict__ m1,
    const float* __restrict__ v1,
    const float* __restrict__ c2b, const float* __restrict__ g2,
    const float* __restrict__ b2,  const float* __restrict__ m2,
    const float* __restrict__ v2,
    const float* __restrict__ c3b, const float* __restrict__ g3,
    const float* __restrict__ b3,  const float* __restrict__ m3,
    const float* __restrict__ v3,
    const float* __restrict__ pfb, const float* __restrict__ vfb,
    const float* __restrict__ mfb,
    float* __restrict__ scale1, float* __restrict__ bias1f,
    float* __restrict__ scale2, float* __restrict__ bias2f,
    float* __restrict__ scale3, float* __restrict__ bias3f,
    float* __restrict__ biasfc)
{
    int t = threadIdx.x;  // 768 threads
    if (t < 64) {
        float s = g1[t] * rsqrtf(v1[t] + 1e-5f);
        scale1[t] = s;
        bias1f[t] = (c1b[t] - m1[t]) * s + b1[t];
    }
    if (t < 128) {
        float s2 = g2[t] * rsqrtf(v2[t] + 1e-5f);
        scale2[t] = s2;
        bias2f[t] = (c2b[t] - m2[t]) * s2 + b2[t];
        float s3 = g3[t] * rsqrtf(v3[t] + 1e-5f);
        scale3[t] = s3;
        bias3f[t] = (c3b[t] - m3[t]) * s3 + b3[t];
    }
    if (t < 256)      biasfc[t] = pfb[t];
    else if (t < 512) biasfc[t] = vfb[t - 256];
    else              biasfc[t] = mfb[t - 512];
}

// conv weights (O, CIN, 3, 3) fp32 -> 3 bf16 planes in FRAG-MAJOR layout:
// dest = kt*4096 + (n>>5)*1024 + ((n>>4)&1)*512 + (kk>>3)*128 + (n&15)*8 + (kk&7)
// so a wave's B-frag read is base + lane*8 elems (lane-contiguous, conflict-free).
template<int CIN>
__global__ void prep_convw_k(const float* __restrict__ w,
                             __hip_bfloat16* __restrict__ wt, size_t planeW)
{
    int id = blockIdx.x * 256 + threadIdx.x;
    int kk = id & 31;
    int n  = (id >> 5) & 127;
    int kt = id >> 12;
    int k  = kt * 32 + kk;
    int s  = k / CIN;
    int i  = k & (CIN - 1);
    __hip_bfloat16 s0, s1, s2;
    split3(w[(n * CIN + i) * 9 + s], s0, s1, s2);
    size_t dest = (size_t)kt * 4096 + ((n >> 5) * 1024) + (((n >> 4) & 1) * 512)
                + ((kk >> 3) * 128) + ((n & 15) * 8) + (kk & 7);
    wt[dest] = s0; wt[dest + planeW] = s1; wt[dest + 2 * planeW] = s2;
}

// fused FC1 weight -> 3 bf16 planes, frag-major per 128-col group:
// dest = kt*24576 + (n>>7)*4096 + ((n>>6)&1)*2048 + ((n>>4)&3)*512 + (kk>>3)*128 + (n&15)*8 + (kk&7)
// k' = kt*32+kk = p*128+c ; orig k = c*36+p
__global__ void prep_bigw_k(const float* __restrict__ pw,
                            const float* __restrict__ vw,
                            const float* __restrict__ mw,
                            __hip_bfloat16* __restrict__ bigw, size_t planeBW)
{
    int id = blockIdx.x * 256 + threadIdx.x;   // < 4608*768
    int kk = id & 31;
    int n  = (id >> 5) % 768;
    int kt = id / (32 * 768);
    int k2 = kt * 32 + kk;
    int c  = k2 & 127, p = k2 >> 7;
    int k  = c * 36 + p;
    float v;
    if (n < 256)      v = pw[n * 4608 + k];
    else if (n < 512) v = vw[(n - 256) * 4608 + k];
    else              v = mw[(n - 512) * 4644 + k];
    __hip_bfloat16 s0, s1, s2;
    split3(v, s0, s1, s2);
    size_t dest = (size_t)kt * 24576 + ((n >> 7) * 4096) + (((n >> 6) & 1) * 2048)
                + (((n >> 4) & 3) * 512) + ((kk >> 3) * 128) + ((n & 15) * 8) + (kk & 7);
    bigw[dest] = s0; bigw[dest + planeBW] = s1; bigw[dest + 2 * planeBW] = s2;
}

__global__ void prep_selw_k(const float* __restrict__ mw,
                            float* __restrict__ selw)
{
    int j = blockIdx.x, d = threadIdx.x;
    selw[j * 256 + d] = mw[d * 4644 + 4608 + j];
}

// ---------------- conv1 (4->64, K=36): exact fp32 VALU, split-stored ----------------

__global__ __launch_bounds__(256)
void conv1_k(const float* __restrict__ x,               // (B,4,36) full
             const float* __restrict__ w,               // (64,4,9)
             const float* __restrict__ scale, const float* __restrict__ biasf,
             __hip_bfloat16* __restrict__ out, size_t planeA,  // 3 planes (CHUNK,36,64)
             int b_base)
{
    __shared__ float wl[64 * 37];
    int tid = threadIdx.x;
    for (int c = tid; c < 64 * 36; c += 256) {
        int o = c / 36, k = c - o * 36;
        wl[o * 37 + k] = w[c];
    }
    __syncthreads();
    unsigned gid = blockIdx.x * 256 + tid;  // local (chunk) b*36*64 range
    int o = gid & 63;
    unsigned bp = gid >> 6;                 // local b*36+p
    unsigned b = bp / 36;
    int p = bp - b * 36;
    int py = p / 6, px = p - py * 6;
    const float* xb = x + (size_t)(b_base + b) * 4 * 36;
    float acc = 0.f;
#pragma unroll
    for (int i = 0; i < 4; ++i) {
#pragma unroll
        for (int s = 0; s < 9; ++s) {
            int ny = py + s / 3 - 1, nx = px + s % 3 - 1;
            if ((unsigned)ny < 6u && (unsigned)nx < 6u)
                acc += xb[i * 36 + ny * 6 + nx] * wl[o * 37 + i * 9 + s];
        }
    }
    float v = fmaxf(acc * scale[o] + biasf[o], 0.f);
    __hip_bfloat16 s0, s1, s2;
    split3(v, s0, s1, s2);
    size_t idx = (size_t)bp * 64 + o;
    out[idx] = s0; out[idx + planeA] = s1; out[idx + 2 * planeA] = s2;
}

// ---------------- conv2/conv3: implicit-im2col MFMA GEMM, 6-term fp32-emulated ----------------
// R3: grouped A-pass structure. A-plane ap pairs with W-planes 0..(2-ap), all
// into the same acc -> each A-fragment is LDS-read ONCE and MFMA'd against all
// paired W-planes. LDS reads halve (1944 -> 972 per wave); A-pass 0 does 54
// MFMA per 9 reads so the MFMA pipe dominates the LDS pipe instead of
// serializing 1:1 with it. Weights stream global->VGPR (frag-major ==
// lane-contiguous), one-kt register double buffer, no barriers in the K-loop.
template<int CIN, int NW>
__device__ __forceinline__ void conv_apass(
    const __hip_bfloat16* __restrict__ smem,      // xs + zero region
    const __hip_bfloat16* __restrict__ wt,        // W-plane 0 base, frag-major
    size_t planeW, f32x4 (&acc)[9][2],
    int m16, int quad, int bo0, int bo1)
{
    constexpr int PS  = CIN + 8;
    constexpr int CPB = CIN / 32;
    constexpr int NSLICE = CPB * 9;
    constexpr int XS_ELEMS = 144 * PS;

    bf16x8 wc[NW][2], wn[NW][2];
#pragma unroll
    for (int w = 0; w < NW; ++w) {
        const __hip_bfloat16* wP = wt + (size_t)w * planeW;
        wc[w][0] = *(const bf16x8*)(wP + bo0);
        wc[w][1] = *(const bf16x8*)(wP + bo1);
    }

    for (int s = 0; s < 9; ++s) {
        const int dy = s / 3 - 1, dx = s % 3 - 1;
        int aoff[9];
#pragma unroll
        for (int rt = 0; rt < 9; ++rt) {
            int m   = rt * 16 + m16;          // 0..143
            int img = m / 36;
            int p   = m - img * 36;
            int py  = p / 6, px = p - py * 6;
            int ny  = py + dy, nx = px + dx;
            bool ok = ((unsigned)ny < 6u) && ((unsigned)nx < 6u);
            int base = ok ? ((img * 36 + ny * 6 + nx) * PS) : XS_ELEMS;
            aoff[rt] = base + quad * 8;
        }
#pragma unroll
        for (int c = 0; c < CPB; ++c) {
            const int kt = s * CPB + c;
            const int ktn = (kt + 1 < NSLICE) ? (kt + 1) : 0;  // clamp: harmless
#pragma unroll
            for (int w = 0; w < NW; ++w) {
                const __hip_bfloat16* wN = wt + (size_t)w * planeW + (size_t)ktn * 4096;
                wn[w][0] = *(const bf16x8*)(wN + bo0);
                wn[w][1] = *(const bf16x8*)(wN + bo1);
            }
            bf16x8 af[9];
            const int coff = c * 32;
#pragma unroll
            for (int rt = 0; rt < 9; ++rt)
                af[rt] = *(const bf16x8*)(smem + aoff[rt] + coff);
            // w-outer / rt-inner: each acc reg touched every 18 MFMAs (no chain stall)
#pragma unroll
            for (int w = 0; w < NW; ++w)
#pragma unroll
                for (int rt = 0; rt < 9; ++rt) {
                    acc[rt][0] = mfma16(af[rt], wc[w][0], acc[rt][0]);
                    acc[rt][1] = mfma16(af[rt], wc[w][1], acc[rt][1]);
                }
#pragma unroll
            for (int w = 0; w < NW; ++w) { wc[w][0] = wn[w][0]; wc[w][1] = wn[w][1]; }
        }
    }
}

template<int CIN>
__global__ __launch_bounds__(256, 2)
void conv_gemm_k(const __hip_bfloat16* __restrict__ in, size_t planeA,   // 3 planes (CHUNK,36,CIN)
                 const __hip_bfloat16* __restrict__ wt, size_t planeW,   // 3 planes frag-major [K/32][4096]
                 const float* __restrict__ scale,
                 const float* __restrict__ biasf,
                 __hip_bfloat16* __restrict__ out, size_t planeO)        // 3 planes (CHUNK,36,128)
{
    constexpr int PS  = CIN + 8;
    constexpr int XS_ELEMS = 144 * PS;
    __shared__ __align__(16) __hip_bfloat16 smem[XS_ELEMS + CIN];  // xs + zero region
    __hip_bfloat16* xs = smem;

    const int tid  = threadIdx.x;
    const int wave = tid >> 6, lane = tid & 63;
    const int m16  = lane & 15, quad = lane >> 4;
    const int b0   = blockIdx.x * 4;   // local image index

    if (tid < CIN) smem[XS_ELEMS + tid] = __float2bfloat16(0.f);  // SAME-pad zeros

    f32x4 acc[9][2];
#pragma unroll
    for (int i = 0; i < 9; ++i) { acc[i][0] = f32x4{0,0,0,0}; acc[i][1] = f32x4{0,0,0,0}; }

    const int bo0 = wave * 1024 + lane * 8;          // ct=0 frag (elems)
    const int bo1 = bo0 + 512;                       // ct=1 frag

    constexpr int CHPP = CIN / 8;
    for (int ap = 0; ap < 3; ++ap) {
        const __hip_bfloat16* inb = in + (size_t)ap * planeA + (size_t)b0 * 36 * CIN;
        __syncthreads();   // previous pass finished all xs reads (covers zs init at ap=0)
        for (int c = tid; c < 144 * CHPP; c += 256) {
            int pix = c / CHPP;
            int off = (c - pix * CHPP) * 8;
            *(int4v*)(xs + pix * PS + off) = *(const int4v*)(inb + pix * CIN + off);
        }
        __syncthreads();
        if      (ap == 0) conv_apass<CIN, 3>(smem, wt, planeW, acc, m16, quad, bo0, bo1);
        else if (ap == 1) conv_apass<CIN, 2>(smem, wt, planeW, acc, m16, quad, bo0, bo1);
        else              conv_apass<CIN, 1>(smem, wt, planeW, acc, m16, quad, bo0, bo1);
    }

    // epilogue: fused BN scale/bias + relu, split-store 3 bf16 planes
#pragma unroll
    for (int ct = 0; ct < 2; ++ct) {
        const int n = wave * 32 + ct * 16 + m16;
        const float sc = scale[n], bi = biasf[n];
#pragma unroll
        for (int rt = 0; rt < 9; ++rt) {
            const int mrow = rt * 16 + quad * 4;
#pragma unroll
            for (int r = 0; r < 4; ++r) {
                float v = fmaxf(acc[rt][ct][r] * sc + bi, 0.f);
                __hip_bfloat16 s0, s1, s2;
                split3(v, s0, s1, s2);
                size_t idx = (size_t)(b0 * 36 + mrow + r) * 128 + n;
                out[idx] = s0; out[idx + planeO] = s1; out[idx + 2 * planeO] = s2;
            }
        }
    }
}

// ---------------- FC1 partial GEMM: B direct global->reg, A LDS-dbuf with
// 2-deep reg pipeline, K-split x2 for occupancy ----------------
// grid = 16 mblk x 6 nblk x 6 pp x 2 ksplit = 1152 blocks
// partial[slot=ks*6+pp] (CHUNK,768) fp32

__global__ __launch_bounds__(256, 3)
void fc_partial_k(const __hip_bfloat16* __restrict__ A, size_t planeF,    // 3 planes (CHUNK,4608)
                  const __hip_bfloat16* __restrict__ Bw, size_t planeBW,  // 3 planes frag-major [144][24576]
                  float* __restrict__ partial)                            // [12](CHUNK,768)
{
    constexpr int ABUF = 4096;              // A elems per buffer (128 rows x 32 k, frag-major)
    __shared__ __align__(16) __hip_bfloat16 smem[2 * ABUF];   // 16 KB
    const int tid = threadIdx.x, wave = tid >> 6, lane = tid & 63;
    const int m16 = lane & 15, quad = lane >> 4;
    const int mblk = blockIdx.x & 15;
    int rest = blockIdx.x >> 4;                 // 0..71
    const int nblk = rest % 6;
    rest /= 6;                                  // 0..11 == output slot
    const int pp = rest % 6;
    const int ks = rest / 6;                    // 0 or 1
    const int kt0 = ks * 72, ktend = kt0 + 72;
    const size_t m0 = (size_t)mblk * 128;
    const int wr = wave >> 1, wc = wave & 1;

    const __hip_bfloat16* Ap = A + (size_t)pair_a(pp) * planeF;
    const __hip_bfloat16* Bp = Bw + (size_t)pair_w(pp) * planeBW + (size_t)nblk * 4096;

    f32x4 acc[4][4];
#pragma unroll
    for (int i = 0; i < 4; ++i)
#pragma unroll
        for (int j = 0; j < 4; ++j) acc[i][j] = f32x4{0,0,0,0};

    const int cr = tid >> 2, co = (tid & 3) * 8;
    // frag-major A-read offsets: base + lane*8 (conflict-free)
    int ao[4];
#pragma unroll
    for (int i = 0; i < 4; ++i) ao[i] = wr * 2048 + i * 512 + lane * 8;
    const int bofs = wc * 2048 + lane * 8;      // B frag offset within kt slice
    const int adst = ((cr >> 4) & 3) * 512 + (tid & 3) * 128 + (cr & 15) * 8;

    auto ldA = [&](int kt, int4v& a0, int4v& a1) {
        const __hip_bfloat16* base = Ap + (m0 + cr) * 4608 + kt * 32 + co;
        a0 = *(const int4v*)base;
        a1 = *(const int4v*)(base + (size_t)64 * 4608);
    };
    auto ldB = [&](int kt, bf16x8* bf) {
        const __hip_bfloat16* base = Bp + (size_t)kt * 24576 + bofs;
#pragma unroll
        for (int i = 0; i < 4; ++i) bf[i] = *(const bf16x8*)(base + i * 512);
    };
    auto stA = [&](int buf, int4v a0, int4v a1) {
        __hip_bfloat16* base = smem + buf * ABUF;
        *(int4v*)(base + adst) = a0;                  // rows 0..63
        *(int4v*)(base + 2048 + adst) = a1;           // rows 64..127
    };

    // prologue: fill 2-deep pipelines
    int4v pa, pb, qa, qb;                 // pa/pb: data for kt+1; qa/qb: in-flight kt+2
    bf16x8 bfc[4], bf1[4];                // bfc: kt (in use), bf1: kt+1
    {
        int4v a0, a1;
        ldA(kt0, a0, a1);
        ldB(kt0, bfc);
        ldA(kt0 + 1, pa, pb);
        ldB(kt0 + 1, bf1);
        stA(0, a0, a1);
    }
    __syncthreads();
    int cur = 0;

#pragma unroll 2
    for (int kt = kt0; kt < ktend; ++kt) {
        const int ktn = (kt + 2 < ktend) ? (kt + 2) : kt0;  // clamp: harmless, in-bounds
        bf16x8 bfn[4];
        ldA(ktn, qa, qb);
        ldB(ktn, bfn);
        const __hip_bfloat16* base = smem + cur * ABUF;
        bf16x8 af[4];
#pragma unroll
        for (int i = 0; i < 4; ++i) af[i] = *(const bf16x8*)(base + ao[i]);
#pragma unroll
        for (int i = 0; i < 4; ++i)
#pragma unroll
            for (int j = 0; j < 4; ++j)
                acc[i][j] = mfma16(af[i], bfc[j], acc[i][j]);
        if (kt + 1 < ktend) stA(cur ^ 1, pa, pb);   // waits loads issued last iter
        __syncthreads();
        cur ^= 1;
        pa = qa; pb = qb;
#pragma unroll
        for (int i = 0; i < 4; ++i) bfc[i] = bf1[i];
#pragma unroll
        for (int i = 0; i < 4; ++i) bf1[i] = bfn[i];
    }

    float* outp = partial + (size_t)rest * CHUNK * 768;   // rest == slot
    const int n0 = nblk * 128;
#pragma unroll
    for (int i = 0; i < 4; ++i) {
        const int row = wr * 64 + i * 16 + quad * 4;
#pragma unroll
        for (int j = 0; j < 4; ++j) {
            const int col = n0 + wc * 64 + j * 16 + m16;
#pragma unroll
            for (int r = 0; r < 4; ++r)
                outp[(m0 + row + r) * 768 + col] = acc[i][j][r];
        }
    }
}

// ---------------- heads: partial-sum + LN + small GEMVs + argmax + dueling (fp32) ----------------

__global__ __launch_bounds__(256)
void heads_k(const float* __restrict__ partial,          // [12](CHUNK,768): [piece|value|move]
             const float* __restrict__ biasfc,           // 768
             const float* __restrict__ pln_g, const float* __restrict__ pln_b,
             const float* __restrict__ pfc2_w, const float* __restrict__ pfc2_b,
             const float* __restrict__ mln_g, const float* __restrict__ mln_b,
             const float* __restrict__ mfc2_w, const float* __restrict__ mfc2_b,
             const float* __restrict__ vln_g, const float* __restrict__ vln_b,
             const float* __restrict__ vfc2_w, const float* __restrict__ vfc2_b,
             const float* __restrict__ selw,             // (36,256)
             float* __restrict__ q,                      // (B,1296) full
             int b_base)
{
    __shared__ float hp[256], hv[256], hm[256];
    __shared__ float pl[36], ml[36];
    __shared__ float red[4];
    __shared__ float valv, plm_s, mlm_s;
    __shared__ int amax_s;

    const int tid = threadIdx.x, wave = tid >> 6, lane = tid & 63;
    const size_t b = blockIdx.x;                // local
    const size_t bg = b_base + b;               // global

    // inline fc-reduce: sum 12 partials + bias
    float pp = biasfc[tid], vv = biasfc[256 + tid], mm = biasfc[512 + tid];
#pragma unroll
    for (int k = 0; k < 12; ++k) {
        const float* row = partial + (size_t)k * CHUNK * 768 + b * 768;
        pp += row[tid]; vv += row[256 + tid]; mm += row[512 + tid];
    }

    auto warpSum = [&](float v) {
        v += __shfl_xor(v, 1);  v += __shfl_xor(v, 2);  v += __shfl_xor(v, 4);
        v += __shfl_xor(v, 8);  v += __shfl_xor(v, 16); v += __shfl_xor(v, 32);
        return v;
    };
    auto blockSum = [&](float v) {
        v = warpSum(v);
        if (lane == 0) red[wave] = v;
        __syncthreads();
        float s = red[0] + red[1] + red[2] + red[3];
        __syncthreads();
        return s;
    };
    auto lnrelu = [&](float x, const float* g, const float* bb) {
        float mu  = blockSum(x) * (1.f / 256.f);
        float d   = x - mu;
        float var = blockSum(d * d) * (1.f / 256.f);
        float y   = d * rsqrtf(var + 1e-5f) * g[tid] + bb[tid];
        return fmaxf(y, 0.f);
    };

    hp[tid] = lnrelu(pp, pln_g, pln_b);
    hv[tid] = lnrelu(vv, vln_g, vln_b);
    __syncthreads();

    {
        float h0 = hp[lane], h1 = hp[64 + lane], h2 = hp[128 + lane], h3 = hp[192 + lane];
#pragma unroll
        for (int jj = 0; jj < 9; ++jj) {
            int j = wave * 9 + jj;
            const float* wr_ = pfc2_w + j * 256;
            float s = h0 * wr_[lane] + h1 * wr_[64 + lane]
                    + h2 * wr_[128 + lane] + h3 * wr_[192 + lane];
            s = warpSum(s);
            if (lane == 0) pl[j] = s + pfc2_b[j];
        }
        if (wave == 0) {
            float g0 = hv[lane], g1 = hv[64 + lane], g2 = hv[128 + lane], g3 = hv[192 + lane];
            float s = g0 * vfc2_w[lane] + g1 * vfc2_w[64 + lane]
                    + g2 * vfc2_w[128 + lane] + g3 * vfc2_w[192 + lane];
            s = warpSum(s);
            if (lane == 0) valv = s + vfc2_b[0];
        }
    }
    __syncthreads();
    if (tid == 0) {   // first-max argmax (jnp semantics) + mean
        float m = -1e30f, s = 0.f; int idx = 0;
        for (int j = 0; j < 36; ++j) { float v = pl[j]; s += v; if (v > m) { m = v; idx = j; } }
        plm_s = s * (1.f / 36.f); amax_s = idx;
    }
    __syncthreads();

    mm += selw[amax_s * 256 + tid];   // one-hot concat == single column add
    hm[tid] = lnrelu(mm, mln_g, mln_b);
    __syncthreads();
    {
        float h0 = hm[lane], h1 = hm[64 + lane], h2 = hm[128 + lane], h3 = hm[192 + lane];
#pragma unroll
        for (int jj = 0; jj < 9; ++jj) {
            int j = wave * 9 + jj;
            const float* wr_ = mfc2_w + j * 256;
            float s = h0 * wr_[lane] + h1 * wr_[64 + lane]
                    + h2 * wr_[128 + lane] + h3 * wr_[192 + lane];
            s = warpSum(s);
            if (lane == 0) ml[j] = s + mfc2_b[j];
        }
    }
    __syncthreads();
    if (tid == 0) {
        float s = 0.f;
        for (int j = 0; j < 36; ++j) s += ml[j];
        mlm_s = s * (1.f / 36.f);
    }
    __syncthreads();

    const float val = valv, plm = plm_s, mlm = mlm_s;
    for (int idx = tid; idx < 1296; idx += 256) {
        int i = idx / 36, j = idx - i * 36;
        q[bg * 1296 + idx] = val + (pl[i] - plm) + (ml[j] - mlm);
    }
}

// ---------------- launch ----------------

extern "C" void kernel_launch(void* const* d_in, const int* in_sizes, int n_in,
                              void* d_out, int out_size, void* d_ws, size_t ws_size,
                              hipStream_t stream)
{
    const float* x       = (const float*)d_in[0];
    const float* conv1_w = (const float*)d_in[1];
    const float* conv1_b = (const float*)d_in[2];
    const float* bn1_g   = (const float*)d_in[3];
    const float* bn1_b   = (const float*)d_in[4];
    const float* bn1_m   = (const float*)d_in[5];
    const float* bn1_v   = (const float*)d_in[6];
    const float* conv2_w = (const float*)d_in[7];
    const float* conv2_b = (const float*)d_in[8];
    const float* bn2_g   = (const float*)d_in[9];
    const float* bn2_b   = (const float*)d_in[10];
    const float* bn2_m   = (const float*)d_in[11];
    const float* bn2_v   = (const float*)d_in[12];
    const float* conv3_w = (const float*)d_in[13];
    const float* conv3_b = (const float*)d_in[14];
    const float* bn3_g   = (const float*)d_in[15];
    const float* bn3_b   = (const float*)d_in[16];
    const float* bn3_m   = (const float*)d_in[17];
    const float* bn3_v   = (const float*)d_in[18];
    const float* pfc1_w  = (const float*)d_in[19];
    const float* pfc1_b  = (const float*)d_in[20];
    const float* pln_g   = (const float*)d_in[21];
    const float* pln_b   = (const float*)d_in[22];
    const float* pfc2_w  = (const float*)d_in[23];
    const float* pfc2_b  = (const float*)d_in[24];
    const float* mfc1_w  = (const float*)d_in[25];
    const float* mfc1_b  = (const float*)d_in[26];
    const float* mln_g   = (const float*)d_in[27];
    const float* mln_b   = (const float*)d_in[28];
    const float* mfc2_w  = (const float*)d_in[29];
    const float* mfc2_b  = (const float*)d_in[30];
    const float* vfc1_w  = (const float*)d_in[31];
    const float* vfc1_b  = (const float*)d_in[32];
    const float* vln_g   = (const float*)d_in[33];
    const float* vln_b   = (const float*)d_in[34];
    const float* vfc2_w  = (const float*)d_in[35];
    const float* vfc2_b  = (const float*)d_in[36];

    const size_t planeW2 = 576 * 128;               // conv2 weight plane elems
    const size_t planeW3 = 1152 * 128;              // conv3 weight plane elems
    const size_t planeBW = (size_t)4608 * 768;      // fc weight plane elems
    const size_t planeA1 = (size_t)CHUNK * 36 * 64; // h1 plane elems (per chunk)
    const size_t planeA2 = (size_t)CHUNK * 36 * 128;// h2/h3 plane elems (per chunk)

    char* ws = (char*)d_ws;
    size_t off = 0;
    auto alloc = [&](size_t bytes) -> char* {
        char* p = ws + off; off += (bytes + 255) & ~(size_t)255; return p;
    };
    __hip_bfloat16* w2t  = (__hip_bfloat16*)alloc(3 * planeW2 * 2);
    __hip_bfloat16* w3t  = (__hip_bfloat16*)alloc(3 * planeW3 * 2);
    __hip_bfloat16* bigw = (__hip_bfloat16*)alloc(3 * planeBW * 2);
    float* selw   = (float*)alloc(36 * 256 * 4);
    float* scale1 = (float*)alloc(64 * 4);
    float* bias1f = (float*)alloc(64 * 4);
    float* scale2 = (float*)alloc(128 * 4);
    float* bias2f = (float*)alloc(128 * 4);
    float* scale3 = (float*)alloc(128 * 4);
    float* bias3f = (float*)alloc(128 * 4);
    float* biasfc = (float*)alloc(768 * 4);
    // ping-pong arenas, per-chunk:
    //   A1: h1 (28.3MB) -> h3 (56.6MB)
    //   A2: h2 (56.6MB) -> fc partials (75.5MB, 12 slots after K-split)
    char* A1 = alloc(3 * planeA2 * 2);                    // 56.6 MB
    char* A2 = alloc((size_t)12 * CHUNK * 768 * 4);       // 75.5 MB
    // total ws ~155 MB (round-2 proved >=196 MB available; round-3 crash proved <475)

    prep_scalars_k<<<1, 768, 0, stream>>>(
        conv1_b, bn1_g, bn1_b, bn1_m, bn1_v,
        conv2_b, bn2_g, bn2_b, bn2_m, bn2_v,
        conv3_b, bn3_g, bn3_b, bn3_m, bn3_v,
        pfc1_b, vfc1_b, mfc1_b,
        scale1, bias1f, scale2, bias2f, scale3, bias3f, biasfc);
    prep_convw_k<64><<<288, 256, 0, stream>>>(conv2_w, w2t, planeW2);
    prep_convw_k<128><<<576, 256, 0, stream>>>(conv3_w, w3t, planeW3);
    prep_bigw_k<<<13824, 256, 0, stream>>>(pfc1_w, vfc1_w, mfc1_w, bigw, planeBW);
    prep_selw_k<<<36, 256, 0, stream>>>(mfc1_w, selw);

    __hip_bfloat16* h1s  = (__hip_bfloat16*)A1;
    __hip_bfloat16* h2s  = (__hip_bfloat16*)A2;
    __hip_bfloat16* h3s  = (__hip_bfloat16*)A1;   // overwrites h1s (dead after conv2)
    float*          fpar = (float*)A2;            // overwrites h2s (dead after conv3)

    for (int cchunk = 0; cchunk < NCHUNK; ++cchunk) {
        const int b_base = cchunk * CHUNK;
        conv1_k<<<CHUNK * 36 * 64 / 256, 256, 0, stream>>>(
            x, conv1_w, scale1, bias1f, h1s, planeA1, b_base);
        conv_gemm_k<64><<<CHUNK / 4, 256, 0, stream>>>(
            h1s, planeA1, w2t, planeW2, scale2, bias2f, h2s, planeA2);
        conv_gemm_k<128><<<CHUNK / 4, 256, 0, stream>>>(
            h2s, planeA2, w3t, planeW3, scale3, bias3f, h3s, planeA2);
        fc_partial_k<<<1152, 256, 0, stream>>>(h3s, planeA2, bigw, planeBW, fpar);
        heads_k<<<CHUNK, 256, 0, stream>>>(fpar, biasfc,
            pln_g, pln_b, pfc2_w, pfc2_b,
            mln_g, mln_b, mfc2_w, mfc2_b,
            vln_g, vln_b, vfc2_w, vfc2_b,
            selw, (float*)d_out, b_base);
    }
}

// Round 4
// 1762.746 us; speedup vs baseline: 1.2531x; 1.2531x over previous
//
#include <hip/hip_runtime.h>
#include <hip/hip_bf16.h>

#define BQ 8192
#define CHUNK 2048
#define NCHUNK 4
typedef __attribute__((ext_vector_type(8))) __bf16 bf16x8;
typedef __attribute__((ext_vector_type(4))) float f32x4;
typedef __attribute__((ext_vector_type(4))) int int4v;

__device__ __forceinline__ f32x4 mfma16(bf16x8 a, bf16x8 b, f32x4 c) {
    return __builtin_amdgcn_mfma_f32_16x16x32_bf16(a, b, c, 0, 0, 0);
}

// 3-way bf16 split of an fp32 value: v ~= s0+s1+s2 to ~2^-25 rel.
__device__ __forceinline__ void split3(float v, __hip_bfloat16& s0,
                                       __hip_bfloat16& s1, __hip_bfloat16& s2) {
    s0 = __float2bfloat16(v);
    float r = v - __bfloat162float(s0);
    s1 = __float2bfloat16(r);
    r -= __bfloat162float(s1);
    s2 = __float2bfloat16(r);
}

// plane-pair schedule for 6-term fp32-emulated product, grouped by A-plane so
// conv kernels can skip xs re-staging: (a,w) = (0,0),(0,1),(0,2),(1,0),(1,1),(2,0)
__device__ __forceinline__ int pair_a(int pp) { return (0x211000 >> (4 * pp)) & 0xF; }
__device__ __forceinline__ int pair_w(int pp) { return (0x010210 >> (4 * pp)) & 0xF; }

// ---------------- prep kernels ----------------

__global__ void prep_scalars_k(
    const float* __restrict__ c1b, const float* __restrict__ g1,
    const float* __restrict__ b1,  const float* __restrict__ m1,
    const float* __restrict__ v1,
    const float* __restrict__ c2b, const float* __restrict__ g2,
    const float* __restrict__ b2,  const float* __restrict__ m2,
    const float* __restrict__ v2,
    const float* __restrict__ c3b, const float* __restrict__ g3,
    const float* __restrict__ b3,  const float* __restrict__ m3,
    const float* __restrict__ v3,
    const float* __restrict__ pfb, const float* __restrict__ vfb,
    const float* __restrict__ mfb,
    float* __restrict__ scale1, float* __restrict__ bias1f,
    float* __restrict__ scale2, float* __restrict__ bias2f,
    float* __restrict__ scale3, float* __restrict__ bias3f,
    float* __restrict__ biasfc)
{
    int t = threadIdx.x;  // 768 threads
    if (t < 64) {
        float s = g1[t] * rsqrtf(v1[t] + 1e-5f);
        scale1[t] = s;
        bias1f[t] = (c1b[t] - m1[t]) * s + b1[t];
    }
    if (t < 128) {
        float s2 = g2[t] * rsqrtf(v2[t] + 1e-5f);
        scale2[t] = s2;
        bias2f[t] = (c2b[t] - m2[t]) * s2 + b2[t];
        float s3 = g3[t] * rsqrtf(v3[t] + 1e-5f);
        scale3[t] = s3;
        bias3f[t] = (c3b[t] - m3[t]) * s3 + b3[t];
    }
    if (t < 256)      biasfc[t] = pfb[t];
    else if (t < 512) biasfc[t] = vfb[t - 256];
    else              biasfc[t] = mfb[t - 512];
}

// conv weights (O, CIN, 3, 3) fp32 -> 3 bf16 planes in FRAG-MAJOR layout:
// dest = kt*4096 + (n>>5)*1024 + ((n>>4)&1)*512 + (kk>>3)*128 + (n&15)*8 + (kk&7)
// so a wave's B-frag read is base + lane*8 elems (lane-contiguous, conflict-free).
template<int CIN>
__global__ void prep_convw_k(const float* __restrict__ w,
                             __hip_bfloat16* __restrict__ wt, size_t planeW)
{
    int id = blockIdx.x * 256 + threadIdx.x;
    int kk = id & 31;
    int n  = (id >> 5) & 127;
    int kt = id >> 12;
    int k  = kt * 32 + kk;
    int s  = k / CIN;
    int i  = k & (CIN - 1);
    __hip_bfloat16 s0, s1, s2;
    split3(w[(n * CIN + i) * 9 + s], s0, s1, s2);
    size_t dest = (size_t)kt * 4096 + ((n >> 5) * 1024) + (((n >> 4) & 1) * 512)
                + ((kk >> 3) * 128) + ((n & 15) * 8) + (kk & 7);
    wt[dest] = s0; wt[dest + planeW] = s1; wt[dest + 2 * planeW] = s2;
}

// fused FC1 weight -> 3 bf16 planes, frag-major per 128-col group:
// dest = kt*24576 + (n>>7)*4096 + ((n>>6)&1)*2048 + ((n>>4)&3)*512 + (kk>>3)*128 + (n&15)*8 + (kk&7)
// k' = kt*32+kk = p*128+c ; orig k = c*36+p
__global__ void prep_bigw_k(const float* __restrict__ pw,
                            const float* __restrict__ vw,
                            const float* __restrict__ mw,
                            __hip_bfloat16* __restrict__ bigw, size_t planeBW)
{
    int id = blockIdx.x * 256 + threadIdx.x;   // < 4608*768
    int kk = id & 31;
    int n  = (id >> 5) % 768;
    int kt = id / (32 * 768);
    int k2 = kt * 32 + kk;
    int c  = k2 & 127, p = k2 >> 7;
    int k  = c * 36 + p;
    float v;
    if (n < 256)      v = pw[n * 4608 + k];
    else if (n < 512) v = vw[(n - 256) * 4608 + k];
    else              v = mw[(n - 512) * 4644 + k];
    __hip_bfloat16 s0, s1, s2;
    split3(v, s0, s1, s2);
    size_t dest = (size_t)kt * 24576 + ((n >> 7) * 4096) + (((n >> 6) & 1) * 2048)
                + (((n >> 4) & 3) * 512) + ((kk >> 3) * 128) + ((n & 15) * 8) + (kk & 7);
    bigw[dest] = s0; bigw[dest + planeBW] = s1; bigw[dest + 2 * planeBW] = s2;
}

__global__ void prep_selw_k(const float* __restrict__ mw,
                            float* __restrict__ selw)
{
    int j = blockIdx.x, d = threadIdx.x;
    selw[j * 256 + d] = mw[d * 4644 + 4608 + j];
}

// ---------------- conv1 (4->64, K=36): exact fp32 VALU, split-stored ----------------

__global__ __launch_bounds__(256)
void conv1_k(const float* __restrict__ x,               // (B,4,36) full
             const float* __restrict__ w,               // (64,4,9)
             const float* __restrict__ scale, const float* __restrict__ biasf,
             __hip_bfloat16* __restrict__ out, size_t planeA,  // 3 planes (CHUNK,36,64)
             int b_base)
{
    __shared__ float wl[64 * 37];
    int tid = threadIdx.x;
    for (int c = tid; c < 64 * 36; c += 256) {
        int o = c / 36, k = c - o * 36;
        wl[o * 37 + k] = w[c];
    }
    __syncthreads();
    unsigned gid = blockIdx.x * 256 + tid;  // local (chunk) b*36*64 range
    int o = gid & 63;
    unsigned bp = gid >> 6;                 // local b*36+p
    unsigned b = bp / 36;
    int p = bp - b * 36;
    int py = p / 6, px = p - py * 6;
    const float* xb = x + (size_t)(b_base + b) * 4 * 36;
    float acc = 0.f;
#pragma unroll
    for (int i = 0; i < 4; ++i) {
#pragma unroll
        for (int s = 0; s < 9; ++s) {
            int ny = py + s / 3 - 1, nx = px + s % 3 - 1;
            if ((unsigned)ny < 6u && (unsigned)nx < 6u)
                acc += xb[i * 36 + ny * 6 + nx] * wl[o * 37 + i * 9 + s];
        }
    }
    float v = fmaxf(acc * scale[o] + biasf[o], 0.f);
    __hip_bfloat16 s0, s1, s2;
    split3(v, s0, s1, s2);
    size_t idx = (size_t)bp * 64 + o;
    out[idx] = s0; out[idx + planeA] = s1; out[idx + 2 * planeA] = s2;
}

// ---------------- conv2/conv3: implicit-im2col MFMA GEMM, 6-term fp32-emulated ----------------
// R4: back to the R2 pass structure (register-budget-safe), but 2 images per
// block (72 rows, 5 row-tiles with half-valid tail) -> grid 1024 = 4 blocks/CU,
// 4 waves/SIMD (was 2). Same LDS/MFMA traffic (+11% tail waste), 2x the
// latency-hiding concurrency; acc drops 72->40 VGPR so launch_bounds(256,4)
// holds without spills. Weights stream global->VGPR (frag-major ==
// lane-contiguous), one-kt register double buffer, no barriers in the K-loop.
template<int CIN>
__global__ __launch_bounds__(256, 4)
void conv_gemm_k(const __hip_bfloat16* __restrict__ in, size_t planeA,   // 3 planes (CHUNK,36,CIN)
                 const __hip_bfloat16* __restrict__ wt, size_t planeW,   // 3 planes frag-major [K/32][4096]
                 const float* __restrict__ scale,
                 const float* __restrict__ biasf,
                 __hip_bfloat16* __restrict__ out, size_t planeO)        // 3 planes (CHUNK,36,128)
{
    constexpr int PS  = CIN + 8;
    constexpr int CPB = CIN / 32;
    constexpr int NSLICE = CPB * 9;
    constexpr int XS_ELEMS = 72 * PS;
    __shared__ __align__(16) __hip_bfloat16 smem[XS_ELEMS + CIN];  // xs + zero region
    __hip_bfloat16* xs = smem;

    const int tid  = threadIdx.x;
    const int wave = tid >> 6, lane = tid & 63;
    const int m16  = lane & 15, quad = lane >> 4;
    const int b0   = blockIdx.x * 2;   // local image index (2 images/block)

    if (tid < CIN) smem[XS_ELEMS + tid] = __float2bfloat16(0.f);  // SAME-pad zeros

    f32x4 acc[5][2];
#pragma unroll
    for (int i = 0; i < 5; ++i) { acc[i][0] = f32x4{0,0,0,0}; acc[i][1] = f32x4{0,0,0,0}; }

    const int bo0 = wave * 1024 + lane * 8;          // ct=0 frag (elems)
    const int bo1 = bo0 + 512;                       // ct=1 frag

    constexpr int CHPP = CIN / 8;
    for (int pp = 0; pp < 6; ++pp) {
        const __hip_bfloat16* inb = in + (size_t)pair_a(pp) * planeA + (size_t)b0 * 36 * CIN;
        const __hip_bfloat16* wP  = wt + (size_t)pair_w(pp) * planeW;
        const bool stage_x = (pp == 0) || (pair_a(pp) != pair_a(pp - 1));

        if (stage_x) {   // block-uniform; only 3 of 6 passes
            __syncthreads();   // all waves done reading previous xs (covers zs init at pp=0)
            for (int c = tid; c < 72 * CHPP; c += 256) {
                int pix = c / CHPP;
                int off = (c - pix * CHPP) * 8;
                *(int4v*)(xs + pix * PS + off) = *(const int4v*)(inb + pix * CIN + off);
            }
            __syncthreads();
        }

        // per-pass prologue: load this wave's kt=0 weight frags straight to VGPRs
        bf16x8 wc0 = *(const bf16x8*)(wP + bo0);
        bf16x8 wc1 = *(const bf16x8*)(wP + bo1);

        for (int s = 0; s < 9; ++s) {
            const int dy = s / 3 - 1, dx = s % 3 - 1;
            int aoff[5];
#pragma unroll
            for (int rt = 0; rt < 5; ++rt) {
                int m   = rt * 16 + m16;          // 0..79; valid < 72
                int img = m >= 36;                // 0 or 1 for valid rows
                int p   = m - img * 36;
                int py  = p / 6, px = p - py * 6;
                int ny  = py + dy, nx = px + dx;
                bool ok = (m < 72) && ((unsigned)ny < 6u) && ((unsigned)nx < 6u);
                int base = ok ? ((img * 36 + ny * 6 + nx) * PS) : XS_ELEMS;
                aoff[rt] = base + quad * 8;
            }
#pragma unroll
            for (int c = 0; c < CPB; ++c) {
                const int kt = s * CPB + c;
                // register double buffer: issue next-slice loads before this
                // slice's MFMAs (clamped to 0 on the last slice -- harmless,
                // branch-free, always in-bounds)
                const int ktn = (kt + 1 < NSLICE) ? (kt + 1) : 0;
                const __hip_bfloat16* wN = wP + (size_t)ktn * 4096;
                bf16x8 wn0 = *(const bf16x8*)(wN + bo0);
                bf16x8 wn1 = *(const bf16x8*)(wN + bo1);
                const int coff = c * 32;
#pragma unroll
                for (int rt = 0; rt < 5; ++rt) {
                    bf16x8 af = *(const bf16x8*)(smem + aoff[rt] + coff);
                    acc[rt][0] = mfma16(af, wc0, acc[rt][0]);
                    acc[rt][1] = mfma16(af, wc1, acc[rt][1]);
                }
                wc0 = wn0; wc1 = wn1;
            }
        }
    }

    // epilogue: fused BN scale/bias + relu, split-store 3 bf16 planes
#pragma unroll
    for (int ct = 0; ct < 2; ++ct) {
        const int n = wave * 32 + ct * 16 + m16;
        const float sc = scale[n], bi = biasf[n];
#pragma unroll
        for (int rt = 0; rt < 5; ++rt) {
            const int mrow = rt * 16 + quad * 4;
            if (mrow < 72) {
#pragma unroll
                for (int r = 0; r < 4; ++r) {
                    float v = fmaxf(acc[rt][ct][r] * sc + bi, 0.f);
                    __hip_bfloat16 s0, s1, s2;
                    split3(v, s0, s1, s2);
                    size_t idx = (size_t)(b0 * 36 + mrow + r) * 128 + n;
                    out[idx] = s0; out[idx + planeO] = s1; out[idx + 2 * planeO] = s2;
                }
            }
        }
    }
}

// ---------------- FC1 partial GEMM: B direct global->reg, A LDS-dbuf with
// 2-deep reg pipeline, K-split x2 for occupancy ----------------
// grid = 16 mblk x 6 nblk x 6 pp x 2 ksplit = 1152 blocks
// partial[slot=ks*6+pp] (CHUNK,768) fp32

__global__ __launch_bounds__(256, 3)
void fc_partial_k(const __hip_bfloat16* __restrict__ A, size_t planeF,    // 3 planes (CHUNK,4608)
                  const __hip_bfloat16* __restrict__ Bw, size_t planeBW,  // 3 planes frag-major [144][24576]
                  float* __restrict__ partial)                            // [12](CHUNK,768)
{
    constexpr int ABUF = 4096;              // A elems per buffer (128 rows x 32 k, frag-major)
    __shared__ __align__(16) __hip_bfloat16 smem[2 * ABUF];   // 16 KB
    const int tid = threadIdx.x, wave = tid >> 6, lane = tid & 63;
    const int m16 = lane & 15, quad = lane >> 4;
    const int mblk = blockIdx.x & 15;
    int rest = blockIdx.x >> 4;                 // 0..71
    const int nblk = rest % 6;
    rest /= 6;                                  // 0..11 == output slot
    const int pp = rest % 6;
    const int ks = rest / 6;                    // 0 or 1
    const int kt0 = ks * 72, ktend = kt0 + 72;
    const size_t m0 = (size_t)mblk * 128;
    const int wr = wave >> 1, wc = wave & 1;

    const __hip_bfloat16* Ap = A + (size_t)pair_a(pp) * planeF;
    const __hip_bfloat16* Bp = Bw + (size_t)pair_w(pp) * planeBW + (size_t)nblk * 4096;

    f32x4 acc[4][4];
#pragma unroll
    for (int i = 0; i < 4; ++i)
#pragma unroll
        for (int j = 0; j < 4; ++j) acc[i][j] = f32x4{0,0,0,0};

    const int cr = tid >> 2, co = (tid & 3) * 8;
    // frag-major A-read offsets: base + lane*8 (conflict-free)
    int ao[4];
#pragma unroll
    for (int i = 0; i < 4; ++i) ao[i] = wr * 2048 + i * 512 + lane * 8;
    const int bofs = wc * 2048 + lane * 8;      // B frag offset within kt slice
    const int adst = ((cr >> 4) & 3) * 512 + (tid & 3) * 128 + (cr & 15) * 8;

    auto ldA = [&](int kt, int4v& a0, int4v& a1) {
        const __hip_bfloat16* base = Ap + (m0 + cr) * 4608 + kt * 32 + co;
        a0 = *(const int4v*)base;
        a1 = *(const int4v*)(base + (size_t)64 * 4608);
    };
    auto ldB = [&](int kt, bf16x8* bf) {
        const __hip_bfloat16* base = Bp + (size_t)kt * 24576 + bofs;
#pragma unroll
        for (int i = 0; i < 4; ++i) bf[i] = *(const bf16x8*)(base + i * 512);
    };
    auto stA = [&](int buf, int4v a0, int4v a1) {
        __hip_bfloat16* base = smem + buf * ABUF;
        *(int4v*)(base + adst) = a0;                  // rows 0..63
        *(int4v*)(base + 2048 + adst) = a1;           // rows 64..127
    };

    // prologue: fill 2-deep pipelines
    int4v pa, pb, qa, qb;                 // pa/pb: data for kt+1; qa/qb: in-flight kt+2
    bf16x8 bfc[4], bf1[4];                // bfc: kt (in use), bf1: kt+1
    {
        int4v a0, a1;
        ldA(kt0, a0, a1);
        ldB(kt0, bfc);
        ldA(kt0 + 1, pa, pb);
        ldB(kt0 + 1, bf1);
        stA(0, a0, a1);
    }
    __syncthreads();
    int cur = 0;

#pragma unroll 2
    for (int kt = kt0; kt < ktend; ++kt) {
        const int ktn = (kt + 2 < ktend) ? (kt + 2) : kt0;  // clamp: harmless, in-bounds
        bf16x8 bfn[4];
        ldA(ktn, qa, qb);
        ldB(ktn, bfn);
        const __hip_bfloat16* base = smem + cur * ABUF;
        bf16x8 af[4];
#pragma unroll
        for (int i = 0; i < 4; ++i) af[i] = *(const bf16x8*)(base + ao[i]);
#pragma unroll
        for (int i = 0; i < 4; ++i)
#pragma unroll
            for (int j = 0; j < 4; ++j)
                acc[i][j] = mfma16(af[i], bfc[j], acc[i][j]);
        if (kt + 1 < ktend) stA(cur ^ 1, pa, pb);   // waits loads issued last iter
        __syncthreads();
        cur ^= 1;
        pa = qa; pb = qb;
#pragma unroll
        for (int i = 0; i < 4; ++i) bfc[i] = bf1[i];
#pragma unroll
        for (int i = 0; i < 4; ++i) bf1[i] = bfn[i];
    }

    float* outp = partial + (size_t)rest * CHUNK * 768;   // rest == slot
    const int n0 = nblk * 128;
#pragma unroll
    for (int i = 0; i < 4; ++i) {
        const int row = wr * 64 + i * 16 + quad * 4;
#pragma unroll
        for (int j = 0; j < 4; ++j) {
            const int col = n0 + wc * 64 + j * 16 + m16;
#pragma unroll
            for (int r = 0; r < 4; ++r)
                outp[(m0 + row + r) * 768 + col] = acc[i][j][r];
        }
    }
}

// ---------------- heads: partial-sum + LN + small GEMVs + argmax + dueling (fp32) ----------------

__global__ __launch_bounds__(256)
void heads_k(const float* __restrict__ partial,          // [12](CHUNK,768): [piece|value|move]
             const float* __restrict__ biasfc,           // 768
             const float* __restrict__ pln_g, const float* __restrict__ pln_b,
             const float* __restrict__ pfc2_w, const float* __restrict__ pfc2_b,
             const float* __restrict__ mln_g, const float* __restrict__ mln_b,
             const float* __restrict__ mfc2_w, const float* __restrict__ mfc2_b,
             const float* __restrict__ vln_g, const float* __restrict__ vln_b,
             const float* __restrict__ vfc2_w, const float* __restrict__ vfc2_b,
             const float* __restrict__ selw,             // (36,256)
             float* __restrict__ q,                      // (B,1296) full
             int b_base)
{
    __shared__ float hp[256], hv[256], hm[256];
    __shared__ float pl[36], ml[36];
    __shared__ float red[4];
    __shared__ float valv, plm_s, mlm_s;
    __shared__ int amax_s;

    const int tid = threadIdx.x, wave = tid >> 6, lane = tid & 63;
    const size_t b = blockIdx.x;                // local
    const size_t bg = b_base + b;               // global

    // inline fc-reduce: sum 12 partials + bias
    float pp = biasfc[tid], vv = biasfc[256 + tid], mm = biasfc[512 + tid];
#pragma unroll
    for (int k = 0; k < 12; ++k) {
        const float* row = partial + (size_t)k * CHUNK * 768 + b * 768;
        pp += row[tid]; vv += row[256 + tid]; mm += row[512 + tid];
    }

    auto warpSum = [&](float v) {
        v += __shfl_xor(v, 1);  v += __shfl_xor(v, 2);  v += __shfl_xor(v, 4);
        v += __shfl_xor(v, 8);  v += __shfl_xor(v, 16); v += __shfl_xor(v, 32);
        return v;
    };
    auto blockSum = [&](float v) {
        v = warpSum(v);
        if (lane == 0) red[wave] = v;
        __syncthreads();
        float s = red[0] + red[1] + red[2] + red[3];
        __syncthreads();
        return s;
    };
    auto lnrelu = [&](float x, const float* g, const float* bb) {
        float mu  = blockSum(x) * (1.f / 256.f);
        float d   = x - mu;
        float var = blockSum(d * d) * (1.f / 256.f);
        float y   = d * rsqrtf(var + 1e-5f) * g[tid] + bb[tid];
        return fmaxf(y, 0.f);
    };

    hp[tid] = lnrelu(pp, pln_g, pln_b);
    hv[tid] = lnrelu(vv, vln_g, vln_b);
    __syncthreads();

    {
        float h0 = hp[lane], h1 = hp[64 + lane], h2 = hp[128 + lane], h3 = hp[192 + lane];
#pragma unroll
        for (int jj = 0; jj < 9; ++jj) {
            int j = wave * 9 + jj;
            const float* wr_ = pfc2_w + j * 256;
            float s = h0 * wr_[lane] + h1 * wr_[64 + lane]
                    + h2 * wr_[128 + lane] + h3 * wr_[192 + lane];
            s = warpSum(s);
            if (lane == 0) pl[j] = s + pfc2_b[j];
        }
        if (wave == 0) {
            float g0 = hv[lane], g1 = hv[64 + lane], g2 = hv[128 + lane], g3 = hv[192 + lane];
            float s = g0 * vfc2_w[lane] + g1 * vfc2_w[64 + lane]
                    + g2 * vfc2_w[128 + lane] + g3 * vfc2_w[192 + lane];
            s = warpSum(s);
            if (lane == 0) valv = s + vfc2_b[0];
        }
    }
    __syncthreads();
    if (tid == 0) {   // first-max argmax (jnp semantics) + mean
        float m = -1e30f, s = 0.f; int idx = 0;
        for (int j = 0; j < 36; ++j) { float v = pl[j]; s += v; if (v > m) { m = v; idx = j; } }
        plm_s = s * (1.f / 36.f); amax_s = idx;
    }
    __syncthreads();

    mm += selw[amax_s * 256 + tid];   // one-hot concat == single column add
    hm[tid] = lnrelu(mm, mln_g, mln_b);
    __syncthreads();
    {
        float h0 = hm[lane], h1 = hm[64 + lane], h2 = hm[128 + lane], h3 = hm[192 + lane];
#pragma unroll
        for (int jj = 0; jj < 9; ++jj) {
            int j = wave * 9 + jj;
            const float* wr_ = mfc2_w + j * 256;
            float s = h0 * wr_[lane] + h1 * wr_[64 + lane]
                    + h2 * wr_[128 + lane] + h3 * wr_[192 + lane];
            s = warpSum(s);
            if (lane == 0) ml[j] = s + mfc2_b[j];
        }
    }
    __syncthreads();
    if (tid == 0) {
        float s = 0.f;
        for (int j = 0; j < 36; ++j) s += ml[j];
        mlm_s = s * (1.f / 36.f);
    }
    __syncthreads();

    const float val = valv, plm = plm_s, mlm = mlm_s;
    for (int idx = tid; idx < 1296; idx += 256) {
        int i = idx / 36, j = idx - i * 36;
        q[bg * 1296 + idx] = val + (pl[i] - plm) + (ml[j] - mlm);
    }
}

// ---------------- launch ----------------

extern "C" void kernel_launch(void* const* d_in, const int* in_sizes, int n_in,
                              void* d_out, int out_size, void* d_ws, size_t ws_size,
                              hipStream_t stream)
{
    const float* x       = (const float*)d_in[0];
    const float* conv1_w = (const float*)d_in[1];
    const float* conv1_b = (const float*)d_in[2];
    const float* bn1_g   = (const float*)d_in[3];
    const float* bn1_b   = (const float*)d_in[4];
    const float* bn1_m   = (const float*)d_in[5];
    const float* bn1_v   = (const float*)d_in[6];
    const float* conv2_w = (const float*)d_in[7];
    const float* conv2_b = (const float*)d_in[8];
    const float* bn2_g   = (const float*)d_in[9];
    const float* bn2_b   = (const float*)d_in[10];
    const float* bn2_m   = (const float*)d_in[11];
    const float* bn2_v   = (const float*)d_in[12];
    const float* conv3_w = (const float*)d_in[13];
    const float* conv3_b = (const float*)d_in[14];
    const float* bn3_g   = (const float*)d_in[15];
    const float* bn3_b   = (const float*)d_in[16];
    const float* bn3_m   = (const float*)d_in[17];
    const float* bn3_v   = (const float*)d_in[18];
    const float* pfc1_w  = (const float*)d_in[19];
    const float* pfc1_b  = (const float*)d_in[20];
    const float* pln_g   = (const float*)d_in[21];
    const float* pln_b   = (const float*)d_in[22];
    const float* pfc2_w  = (const float*)d_in[23];
    const float* pfc2_b  = (const float*)d_in[24];
    const float* mfc1_w  = (const float*)d_in[25];
    const float* mfc1_b  = (const float*)d_in[26];
    const float* mln_g   = (const float*)d_in[27];
    const float* mln_b   = (const float*)d_in[28];
    const float* mfc2_w  = (const float*)d_in[29];
    const float* mfc2_b  = (const float*)d_in[30];
    const float* vfc1_w  = (const float*)d_in[31];
    const float* vfc1_b  = (const float*)d_in[32];
    const float* vln_g   = (const float*)d_in[33];
    const float* vln_b   = (const float*)d_in[34];
    const float* vfc2_w  = (const float*)d_in[35];
    const float* vfc2_b  = (const float*)d_in[36];

    const size_t planeW2 = 576 * 128;               // conv2 weight plane elems
    const size_t planeW3 = 1152 * 128;              // conv3 weight plane elems
    const size_t planeBW = (size_t)4608 * 768;      // fc weight plane elems
    const size_t planeA1 = (size_t)CHUNK * 36 * 64; // h1 plane elems (per chunk)
    const size_t planeA2 = (size_t)CHUNK * 36 * 128;// h2/h3 plane elems (per chunk)

    char* ws = (char*)d_ws;
    size_t off = 0;
    auto alloc = [&](size_t bytes) -> char* {
        char* p = ws + off; off += (bytes + 255) & ~(size_t)255; return p;
    };
    __hip_bfloat16* w2t  = (__hip_bfloat16*)alloc(3 * planeW2 * 2);
    __hip_bfloat16* w3t  = (__hip_bfloat16*)alloc(3 * planeW3 * 2);
    __hip_bfloat16* bigw = (__hip_bfloat16*)alloc(3 * planeBW * 2);
    float* selw   = (float*)alloc(36 * 256 * 4);
    float* scale1 = (float*)alloc(64 * 4);
    float* bias1f = (float*)alloc(64 * 4);
    float* scale2 = (float*)alloc(128 * 4);
    float* bias2f = (float*)alloc(128 * 4);
    float* scale3 = (float*)alloc(128 * 4);
    float* bias3f = (float*)alloc(128 * 4);
    float* biasfc = (float*)alloc(768 * 4);
    // ping-pong arenas, per-chunk:
    //   A1: h1 (28.3MB) -> h3 (56.6MB)
    //   A2: h2 (56.6MB) -> fc partials (75.5MB, 12 slots after K-split)
    char* A1 = alloc(3 * planeA2 * 2);                    // 56.6 MB
    char* A2 = alloc((size_t)12 * CHUNK * 768 * 4);       // 75.5 MB
    // total ws ~155 MB (round-2 proved >=196 MB available; round-3 crash proved <475)

    prep_scalars_k<<<1, 768, 0, stream>>>(
        conv1_b, bn1_g, bn1_b, bn1_m, bn1_v,
        conv2_b, bn2_g, bn2_b, bn2_m, bn2_v,
        conv3_b, bn3_g, bn3_b, bn3_m, bn3_v,
        pfc1_b, vfc1_b, mfc1_b,
        scale1, bias1f, scale2, bias2f, scale3, bias3f, biasfc);
    prep_convw_k<64><<<288, 256, 0, stream>>>(conv2_w, w2t, planeW2);
    prep_convw_k<128><<<576, 256, 0, stream>>>(conv3_w, w3t, planeW3);
    prep_bigw_k<<<13824, 256, 0, stream>>>(pfc1_w, vfc1_w, mfc1_w, bigw, planeBW);
    prep_selw_k<<<36, 256, 0, stream>>>(mfc1_w, selw);

    __hip_bfloat16* h1s  = (__hip_bfloat16*)A1;
    __hip_bfloat16* h2s  = (__hip_bfloat16*)A2;
    __hip_bfloat16* h3s  = (__hip_bfloat16*)A1;   // overwrites h1s (dead after conv2)
    float*          fpar = (float*)A2;            // overwrites h2s (dead after conv3)

    for (int cchunk = 0; cchunk < NCHUNK; ++cchunk) {
        const int b_base = cchunk * CHUNK;
        conv1_k<<<CHUNK * 36 * 64 / 256, 256, 0, stream>>>(
            x, conv1_w, scale1, bias1f, h1s, planeA1, b_base);
        conv_gemm_k<64><<<CHUNK / 2, 256, 0, stream>>>(
            h1s, planeA1, w2t, planeW2, scale2, bias2f, h2s, planeA2);
        conv_gemm_k<128><<<CHUNK / 2, 256, 0, stream>>>(
            h2s, planeA2, w3t, planeW3, scale3, bias3f, h3s, planeA2);
        fc_partial_k<<<1152, 256, 0, stream>>>(h3s, planeA2, bigw, planeBW, fpar);
        heads_k<<<CHUNK, 256, 0, stream>>>(fpar, biasfc,
            pln_g, pln_b, pfc2_w, pfc2_b,
            mln_g, mln_b, mfc2_w, mfc2_b,
            vln_g, vln_b, vfc2_w, vfc2_b,
            selw, (float*)d_out, b_base);
    }
}

// Round 5
// 1697.673 us; speedup vs baseline: 1.3012x; 1.0383x over previous
//
#include <hip/hip_runtime.h>
#include <hip/hip_bf16.h>

#define BQ 8192
#define CHUNK 2048
#define NCHUNK 4
typedef __attribute__((ext_vector_type(8))) __bf16 bf16x8;
typedef __attribute__((ext_vector_type(4))) float f32x4;
typedef __attribute__((ext_vector_type(4))) int int4v;

__device__ __forceinline__ f32x4 mfma16(bf16x8 a, bf16x8 b, f32x4 c) {
    return __builtin_amdgcn_mfma_f32_16x16x32_bf16(a, b, c, 0, 0, 0);
}

// 3-way bf16 split of an fp32 value: v ~= s0+s1+s2 to ~2^-25 rel.
__device__ __forceinline__ void split3(float v, __hip_bfloat16& s0,
                                       __hip_bfloat16& s1, __hip_bfloat16& s2) {
    s0 = __float2bfloat16(v);
    float r = v - __bfloat162float(s0);
    s1 = __float2bfloat16(r);
    r -= __bfloat162float(s1);
    s2 = __float2bfloat16(r);
}

// plane-pair schedule for 6-term fp32-emulated product, grouped by A-plane:
// (a,w) = (0,0),(0,1),(0,2),(1,0),(1,1),(2,0) == A-plane g x W-planes 0..(2-g).
// conv_gemm uses pair_a/pair_w order; fc_partial uses the grouped form directly.
__device__ __forceinline__ int pair_a(int pp) { return (0x211000 >> (4 * pp)) & 0xF; }
__device__ __forceinline__ int pair_w(int pp) { return (0x010210 >> (4 * pp)) & 0xF; }

// ---------------- prep kernels ----------------

__global__ void prep_scalars_k(
    const float* __restrict__ c1b, const float* __restrict__ g1,
    const float* __restrict__ b1,  const float* __restrict__ m1,
    const float* __restrict__ v1,
    const float* __restrict__ c2b, const float* __restrict__ g2,
    const float* __restrict__ b2,  const float* __restrict__ m2,
    const float* __restrict__ v2,
    const float* __restrict__ c3b, const float* __restrict__ g3,
    const float* __restrict__ b3,  const float* __restrict__ m3,
    const float* __restrict__ v3,
    const float* __restrict__ pfb, const float* __restrict__ vfb,
    const float* __restrict__ mfb,
    float* __restrict__ scale1, float* __restrict__ bias1f,
    float* __restrict__ scale2, float* __restrict__ bias2f,
    float* __restrict__ scale3, float* __restrict__ bias3f,
    float* __restrict__ biasfc)
{
    int t = threadIdx.x;  // 768 threads
    if (t < 64) {
        float s = g1[t] * rsqrtf(v1[t] + 1e-5f);
        scale1[t] = s;
        bias1f[t] = (c1b[t] - m1[t]) * s + b1[t];
    }
    if (t < 128) {
        float s2 = g2[t] * rsqrtf(v2[t] + 1e-5f);
        scale2[t] = s2;
        bias2f[t] = (c2b[t] - m2[t]) * s2 + b2[t];
        float s3 = g3[t] * rsqrtf(v3[t] + 1e-5f);
        scale3[t] = s3;
        bias3f[t] = (c3b[t] - m3[t]) * s3 + b3[t];
    }
    if (t < 256)      biasfc[t] = pfb[t];
    else if (t < 512) biasfc[t] = vfb[t - 256];
    else              biasfc[t] = mfb[t - 512];
}

// conv weights (O, CIN, 3, 3) fp32 -> 3 bf16 planes in FRAG-MAJOR layout:
// dest = kt*4096 + (n>>5)*1024 + ((n>>4)&1)*512 + (kk>>3)*128 + (n&15)*8 + (kk&7)
// so a wave's B-frag read is base + lane*8 elems (lane-contiguous, conflict-free).
template<int CIN>
__global__ void prep_convw_k(const float* __restrict__ w,
                             __hip_bfloat16* __restrict__ wt, size_t planeW)
{
    int id = blockIdx.x * 256 + threadIdx.x;
    int kk = id & 31;
    int n  = (id >> 5) & 127;
    int kt = id >> 12;
    int k  = kt * 32 + kk;
    int s  = k / CIN;
    int i  = k & (CIN - 1);
    __hip_bfloat16 s0, s1, s2;
    split3(w[(n * CIN + i) * 9 + s], s0, s1, s2);
    size_t dest = (size_t)kt * 4096 + ((n >> 5) * 1024) + (((n >> 4) & 1) * 512)
                + ((kk >> 3) * 128) + ((n & 15) * 8) + (kk & 7);
    wt[dest] = s0; wt[dest + planeW] = s1; wt[dest + 2 * planeW] = s2;
}

// fused FC1 weight -> 3 bf16 planes, frag-major per 128-col group:
// dest = kt*24576 + (n>>7)*4096 + ((n>>6)&1)*2048 + ((n>>4)&3)*512 + (kk>>3)*128 + (n&15)*8 + (kk&7)
// k' = kt*32+kk = p*128+c ; orig k = c*36+p
__global__ void prep_bigw_k(const float* __restrict__ pw,
                            const float* __restrict__ vw,
                            const float* __restrict__ mw,
                            __hip_bfloat16* __restrict__ bigw, size_t planeBW)
{
    int id = blockIdx.x * 256 + threadIdx.x;   // < 4608*768
    int kk = id & 31;
    int n  = (id >> 5) % 768;
    int kt = id / (32 * 768);
    int k2 = kt * 32 + kk;
    int c  = k2 & 127, p = k2 >> 7;
    int k  = c * 36 + p;
    float v;
    if (n < 256)      v = pw[n * 4608 + k];
    else if (n < 512) v = vw[(n - 256) * 4608 + k];
    else              v = mw[(n - 512) * 4644 + k];
    __hip_bfloat16 s0, s1, s2;
    split3(v, s0, s1, s2);
    size_t dest = (size_t)kt * 24576 + ((n >> 7) * 4096) + (((n >> 6) & 1) * 2048)
                + (((n >> 4) & 3) * 512) + ((kk >> 3) * 128) + ((n & 15) * 8) + (kk & 7);
    bigw[dest] = s0; bigw[dest + planeBW] = s1; bigw[dest + 2 * planeBW] = s2;
}

__global__ void prep_selw_k(const float* __restrict__ mw,
                            float* __restrict__ selw)
{
    int j = blockIdx.x, d = threadIdx.x;
    selw[j * 256 + d] = mw[d * 4644 + 4608 + j];
}

// ---------------- conv1 (4->64, K=36): exact fp32 VALU, split-stored ----------------

__global__ __launch_bounds__(256)
void conv1_k(const float* __restrict__ x,               // (B,4,36) full
             const float* __restrict__ w,               // (64,4,9)
             const float* __restrict__ scale, const float* __restrict__ biasf,
             __hip_bfloat16* __restrict__ out, size_t planeA,  // 3 planes (CHUNK,36,64)
             int b_base)
{
    __shared__ float wl[64 * 37];
    int tid = threadIdx.x;
    for (int c = tid; c < 64 * 36; c += 256) {
        int o = c / 36, k = c - o * 36;
        wl[o * 37 + k] = w[c];
    }
    __syncthreads();
    unsigned gid = blockIdx.x * 256 + tid;  // local (chunk) b*36*64 range
    int o = gid & 63;
    unsigned bp = gid >> 6;                 // local b*36+p
    unsigned b = bp / 36;
    int p = bp - b * 36;
    int py = p / 6, px = p - py * 6;
    const float* xb = x + (size_t)(b_base + b) * 4 * 36;
    float acc = 0.f;
#pragma unroll
    for (int i = 0; i < 4; ++i) {
#pragma unroll
        for (int s = 0; s < 9; ++s) {
            int ny = py + s / 3 - 1, nx = px + s % 3 - 1;
            if ((unsigned)ny < 6u && (unsigned)nx < 6u)
                acc += xb[i * 36 + ny * 6 + nx] * wl[o * 37 + i * 9 + s];
        }
    }
    float v = fmaxf(acc * scale[o] + biasf[o], 0.f);
    __hip_bfloat16 s0, s1, s2;
    split3(v, s0, s1, s2);
    size_t idx = (size_t)bp * 64 + o;
    out[idx] = s0; out[idx + planeA] = s1; out[idx + 2 * planeA] = s2;
}

// ---------------- conv2/conv3: implicit-im2col MFMA GEMM, 6-term fp32-emulated ----------------
// 2 images per block (72 rows, 5 row-tiles with half-valid tail) -> grid 1024,
// 4 blocks/CU. Weights stream global->VGPR (frag-major == lane-contiguous),
// one-kt register double buffer, no barriers in the K-loop.
template<int CIN>
__global__ __launch_bounds__(256, 4)
void conv_gemm_k(const __hip_bfloat16* __restrict__ in, size_t planeA,   // 3 planes (CHUNK,36,CIN)
                 const __hip_bfloat16* __restrict__ wt, size_t planeW,   // 3 planes frag-major [K/32][4096]
                 const float* __restrict__ scale,
                 const float* __restrict__ biasf,
                 __hip_bfloat16* __restrict__ out, size_t planeO)        // 3 planes (CHUNK,36,128)
{
    constexpr int PS  = CIN + 8;
    constexpr int CPB = CIN / 32;
    constexpr int NSLICE = CPB * 9;
    constexpr int XS_ELEMS = 72 * PS;
    __shared__ __align__(16) __hip_bfloat16 smem[XS_ELEMS + CIN];  // xs + zero region
    __hip_bfloat16* xs = smem;

    const int tid  = threadIdx.x;
    const int wave = tid >> 6, lane = tid & 63;
    const int m16  = lane & 15, quad = lane >> 4;
    const int b0   = blockIdx.x * 2;   // local image index (2 images/block)

    if (tid < CIN) smem[XS_ELEMS + tid] = __float2bfloat16(0.f);  // SAME-pad zeros

    f32x4 acc[5][2];
#pragma unroll
    for (int i = 0; i < 5; ++i) { acc[i][0] = f32x4{0,0,0,0}; acc[i][1] = f32x4{0,0,0,0}; }

    const int bo0 = wave * 1024 + lane * 8;          // ct=0 frag (elems)
    const int bo1 = bo0 + 512;                       // ct=1 frag

    constexpr int CHPP = CIN / 8;
    for (int pp = 0; pp < 6; ++pp) {
        const __hip_bfloat16* inb = in + (size_t)pair_a(pp) * planeA + (size_t)b0 * 36 * CIN;
        const __hip_bfloat16* wP  = wt + (size_t)pair_w(pp) * planeW;
        const bool stage_x = (pp == 0) || (pair_a(pp) != pair_a(pp - 1));

        if (stage_x) {   // block-uniform; only 3 of 6 passes
            __syncthreads();   // all waves done reading previous xs (covers zs init at pp=0)
            for (int c = tid; c < 72 * CHPP; c += 256) {
                int pix = c / CHPP;
                int off = (c - pix * CHPP) * 8;
                *(int4v*)(xs + pix * PS + off) = *(const int4v*)(inb + pix * CIN + off);
            }
            __syncthreads();
        }

        // per-pass prologue: load this wave's kt=0 weight frags straight to VGPRs
        bf16x8 wc0 = *(const bf16x8*)(wP + bo0);
        bf16x8 wc1 = *(const bf16x8*)(wP + bo1);

        for (int s = 0; s < 9; ++s) {
            const int dy = s / 3 - 1, dx = s % 3 - 1;
            int aoff[5];
#pragma unroll
            for (int rt = 0; rt < 5; ++rt) {
                int m   = rt * 16 + m16;          // 0..79; valid < 72
                int img = m >= 36;                // 0 or 1 for valid rows
                int p   = m - img * 36;
                int py  = p / 6, px = p - py * 6;
                int ny  = py + dy, nx = px + dx;
                bool ok = (m < 72) && ((unsigned)ny < 6u) && ((unsigned)nx < 6u);
                int base = ok ? ((img * 36 + ny * 6 + nx) * PS) : XS_ELEMS;
                aoff[rt] = base + quad * 8;
            }
#pragma unroll
            for (int c = 0; c < CPB; ++c) {
                const int kt = s * CPB + c;
                const int ktn = (kt + 1 < NSLICE) ? (kt + 1) : 0;
                const __hip_bfloat16* wN = wP + (size_t)ktn * 4096;
                bf16x8 wn0 = *(const bf16x8*)(wN + bo0);
                bf16x8 wn1 = *(const bf16x8*)(wN + bo1);
                const int coff = c * 32;
#pragma unroll
                for (int rt = 0; rt < 5; ++rt) {
                    bf16x8 af = *(const bf16x8*)(smem + aoff[rt] + coff);
                    acc[rt][0] = mfma16(af, wc0, acc[rt][0]);
                    acc[rt][1] = mfma16(af, wc1, acc[rt][1]);
                }
                wc0 = wn0; wc1 = wn1;
            }
        }
    }

    // epilogue: fused BN scale/bias + relu, split-store 3 bf16 planes
#pragma unroll
    for (int ct = 0; ct < 2; ++ct) {
        const int n = wave * 32 + ct * 16 + m16;
        const float sc = scale[n], bi = biasf[n];
#pragma unroll
        for (int rt = 0; rt < 5; ++rt) {
            const int mrow = rt * 16 + quad * 4;
            if (mrow < 72) {
#pragma unroll
                for (int r = 0; r < 4; ++r) {
                    float v = fmaxf(acc[rt][ct][r] * sc + bi, 0.f);
                    __hip_bfloat16 s0, s1, s2;
                    split3(v, s0, s1, s2);
                    size_t idx = (size_t)(b0 * 36 + mrow + r) * 128 + n;
                    out[idx] = s0; out[idx + planeO] = s1; out[idx + 2 * planeO] = s2;
                }
            }
        }
    }
}

// ---------------- FC1 partial GEMM (R5): A-plane grouped ----------------
// All 12 partial slots are summed in heads_k, so a block may accumulate several
// plane-pairs into ONE acc. Group by A-plane: g0 = A0 x {W0,W1,W2} (NW=3),
// g1 = A1 x {W0,W1} (NW=2), g2 = A2 x {W0} (NW=1). Work balanced by K-split
// inversely to NW: NKT = 24/36/72 -> every block does NW*NKT = 72 phase-units.
// A is staged once per kt and reused over NW B-phases; one barrier per kt
// (48 MFMA/barrier for g0). A-prefetch slack 2 kt; B 2-phase register pipeline.
// grid = 16 mblk x 6 nblk x 12 slots = 1152; slots: 0-5=g0, 6-9=g1, 10-11=g2.

template<int NW, int NKT>
__device__ __forceinline__ void fc_body(
    const __hip_bfloat16* __restrict__ Ap,    // A-plane base (g applied)
    const __hip_bfloat16* __restrict__ Bp,    // Bw + nblk*4096 (W-plane 0)
    size_t planeBW, int kt0,
    float* __restrict__ outp, size_t m0,
    __hip_bfloat16* smem, int tid, int wave, int lane)
{
    constexpr int ABUF = 4096;
    constexpr int NPH = NW * NKT;
    const int m16 = lane & 15, quad = lane >> 4;
    const int wr = wave >> 1, wc = wave & 1;
    const int cr = tid >> 2, co = (tid & 3) * 8;

    f32x4 acc[4][4];
#pragma unroll
    for (int i = 0; i < 4; ++i)
#pragma unroll
        for (int j = 0; j < 4; ++j) acc[i][j] = f32x4{0,0,0,0};

    int ao[4];
#pragma unroll
    for (int i = 0; i < 4; ++i) ao[i] = wr * 2048 + i * 512 + lane * 8;
    const int bofs = wc * 2048 + lane * 8;
    const int adst = ((cr >> 4) & 3) * 512 + (tid & 3) * 128 + (cr & 15) * 8;

    auto ldA = [&](int ktr, int4v& a0, int4v& a1) {   // ktr relative to kt0
        const __hip_bfloat16* base = Ap + (m0 + cr) * 4608 + (kt0 + ktr) * 32 + co;
        a0 = *(const int4v*)base;
        a1 = *(const int4v*)(base + (size_t)64 * 4608);
    };
    auto ldB = [&](int p, bf16x8* bf) {               // phase p -> (ktr, w)
        const int ktr = p / NW, w = p - ktr * NW;
        const __hip_bfloat16* base = Bp + (size_t)w * planeBW
                                   + (size_t)(kt0 + ktr) * 24576 + bofs;
#pragma unroll
        for (int i = 0; i < 4; ++i) bf[i] = *(const bf16x8*)(base + i * 512);
    };
    auto stA = [&](int buf, int4v a0, int4v a1) {
        __hip_bfloat16* base = smem + buf * ABUF;
        *(int4v*)(base + adst) = a0;                  // rows 0..63
        *(int4v*)(base + 2048 + adst) = a1;           // rows 64..127
    };

    // prologue
    int4v pa0, pa1, qa0, qa1;
    bf16x8 Bc[4], B1[4], Bn[4];
    {
        int4v a0, a1;
        ldA(0, a0, a1);
        ldB(0, Bc);
        ldA(1, pa0, pa1);
        if (NPH > 1) ldB(1, B1);
        stA(0, a0, a1);
    }
    __syncthreads();
    int cur = 0;

    for (int ktr = 0; ktr < NKT; ++ktr) {
        // A prefetch, 2-kt slack
        { int ktn = (ktr + 2 < NKT) ? (ktr + 2) : 0; ldA(ktn, qa0, qa1); }
        // A fragments for this kt, shared across all NW B-phases
        const __hip_bfloat16* base = smem + cur * ABUF;
        bf16x8 af[4];
#pragma unroll
        for (int i = 0; i < 4; ++i) af[i] = *(const bf16x8*)(base + ao[i]);
#pragma unroll
        for (int w = 0; w < NW; ++w) {
            int p2 = ktr * NW + w + 2;
            if (p2 >= NPH) p2 = 0;                    // clamp: harmless, in-bounds
            ldB(p2, Bn);
#pragma unroll
            for (int i = 0; i < 4; ++i)
#pragma unroll
                for (int j = 0; j < 4; ++j)
                    acc[i][j] = mfma16(af[i], Bc[j], acc[i][j]);
#pragma unroll
            for (int i = 0; i < 4; ++i) { Bc[i] = B1[i]; B1[i] = Bn[i]; }
        }
        if (ktr + 1 < NKT) stA(cur ^ 1, pa0, pa1);    // waits loads issued last kt
        __syncthreads();
        cur ^= 1;
        pa0 = qa0; pa1 = qa1;
    }

#pragma unroll
    for (int i = 0; i < 4; ++i) {
        const int row = wr * 64 + i * 16 + quad * 4;
#pragma unroll
        for (int j = 0; j < 4; ++j) {
            const int col = wc * 64 + j * 16 + m16;
#pragma unroll
            for (int r = 0; r < 4; ++r)
                outp[(m0 + row + r) * 768 + col] = acc[i][j][r];
        }
    }
}

__global__ __launch_bounds__(256, 3)
void fc_partial_k(const __hip_bfloat16* __restrict__ A, size_t planeF,    // 3 planes (CHUNK,4608)
                  const __hip_bfloat16* __restrict__ Bw, size_t planeBW,  // 3 planes frag-major [144][24576]
                  float* __restrict__ partial)                            // [12](CHUNK,768)
{
    constexpr int ABUF = 4096;
    __shared__ __align__(16) __hip_bfloat16 smem[2 * ABUF];   // 16 KB
    const int tid = threadIdx.x, wave = tid >> 6, lane = tid & 63;
    const int mblk = blockIdx.x & 15;
    int rest = blockIdx.x >> 4;                 // 0..71
    const int nblk = rest % 6;
    const int slot = rest / 6;                  // 0..11
    const size_t m0 = (size_t)mblk * 128;

    const __hip_bfloat16* Bp = Bw + (size_t)nblk * 4096;
    float* outp = partial + (size_t)slot * CHUNK * 768 + (size_t)nblk * 128;

    if (slot < 6) {          // g0: A-plane 0, W-planes 0..2, 24 kt
        fc_body<3, 24>(A, Bp, planeBW, slot * 24, outp, m0, smem, tid, wave, lane);
    } else if (slot < 10) {  // g1: A-plane 1, W-planes 0..1, 36 kt
        fc_body<2, 36>(A + planeF, Bp, planeBW, (slot - 6) * 36, outp, m0, smem, tid, wave, lane);
    } else {                 // g2: A-plane 2, W-plane 0, 72 kt
        fc_body<1, 72>(A + 2 * planeF, Bp, planeBW, (slot - 10) * 72, outp, m0, smem, tid, wave, lane);
    }
}

// ---------------- heads: partial-sum + LN + small GEMVs + argmax + dueling (fp32) ----------------

__global__ __launch_bounds__(256)
void heads_k(const float* __restrict__ partial,          // [12](CHUNK,768): [piece|value|move]
             const float* __restrict__ biasfc,           // 768
             const float* __restrict__ pln_g, const float* __restrict__ pln_b,
             const float* __restrict__ pfc2_w, const float* __restrict__ pfc2_b,
             const float* __restrict__ mln_g, const float* __restrict__ mln_b,
             const float* __restrict__ mfc2_w, const float* __restrict__ mfc2_b,
             const float* __restrict__ vln_g, const float* __restrict__ vln_b,
             const float* __restrict__ vfc2_w, const float* __restrict__ vfc2_b,
             const float* __restrict__ selw,             // (36,256)
             float* __restrict__ q,                      // (B,1296) full
             int b_base)
{
    __shared__ float hp[256], hv[256], hm[256];
    __shared__ float pl[36], ml[36];
    __shared__ float red[4];
    __shared__ float valv, plm_s, mlm_s;
    __shared__ int amax_s;

    const int tid = threadIdx.x, wave = tid >> 6, lane = tid & 63;
    const size_t b = blockIdx.x;                // local
    const size_t bg = b_base + b;               // global

    // inline fc-reduce: sum 12 partials + bias
    float pp = biasfc[tid], vv = biasfc[256 + tid], mm = biasfc[512 + tid];
#pragma unroll
    for (int k = 0; k < 12; ++k) {
        const float* row = partial + (size_t)k * CHUNK * 768 + b * 768;
        pp += row[tid]; vv += row[256 + tid]; mm += row[512 + tid];
    }

    auto warpSum = [&](float v) {
        v += __shfl_xor(v, 1);  v += __shfl_xor(v, 2);  v += __shfl_xor(v, 4);
        v += __shfl_xor(v, 8);  v += __shfl_xor(v, 16); v += __shfl_xor(v, 32);
        return v;
    };
    auto blockSum = [&](float v) {
        v = warpSum(v);
        if (lane == 0) red[wave] = v;
        __syncthreads();
        float s = red[0] + red[1] + red[2] + red[3];
        __syncthreads();
        return s;
    };
    auto lnrelu = [&](float x, const float* g, const float* bb) {
        float mu  = blockSum(x) * (1.f / 256.f);
        float d   = x - mu;
        float var = blockSum(d * d) * (1.f / 256.f);
        float y   = d * rsqrtf(var + 1e-5f) * g[tid] + bb[tid];
        return fmaxf(y, 0.f);
    };

    hp[tid] = lnrelu(pp, pln_g, pln_b);
    hv[tid] = lnrelu(vv, vln_g, vln_b);
    __syncthreads();

    {
        float h0 = hp[lane], h1 = hp[64 + lane], h2 = hp[128 + lane], h3 = hp[192 + lane];
#pragma unroll
        for (int jj = 0; jj < 9; ++jj) {
            int j = wave * 9 + jj;
            const float* wr_ = pfc2_w + j * 256;
            float s = h0 * wr_[lane] + h1 * wr_[64 + lane]
                    + h2 * wr_[128 + lane] + h3 * wr_[192 + lane];
            s = warpSum(s);
            if (lane == 0) pl[j] = s + pfc2_b[j];
        }
        if (wave == 0) {
            float g0 = hv[lane], g1 = hv[64 + lane], g2 = hv[128 + lane], g3 = hv[192 + lane];
            float s = g0 * vfc2_w[lane] + g1 * vfc2_w[64 + lane]
                    + g2 * vfc2_w[128 + lane] + g3 * vfc2_w[192 + lane];
            s = warpSum(s);
            if (lane == 0) valv = s + vfc2_b[0];
        }
    }
    __syncthreads();
    if (tid == 0) {   // first-max argmax (jnp semantics) + mean
        float m = -1e30f, s = 0.f; int idx = 0;
        for (int j = 0; j < 36; ++j) { float v = pl[j]; s += v; if (v > m) { m = v; idx = j; } }
        plm_s = s * (1.f / 36.f); amax_s = idx;
    }
    __syncthreads();

    mm += selw[amax_s * 256 + tid];   // one-hot concat == single column add
    hm[tid] = lnrelu(mm, mln_g, mln_b);
    __syncthreads();
    {
        float h0 = hm[lane], h1 = hm[64 + lane], h2 = hm[128 + lane], h3 = hm[192 + lane];
#pragma unroll
        for (int jj = 0; jj < 9; ++jj) {
            int j = wave * 9 + jj;
            const float* wr_ = mfc2_w + j * 256;
            float s = h0 * wr_[lane] + h1 * wr_[64 + lane]
                    + h2 * wr_[128 + lane] + h3 * wr_[192 + lane];
            s = warpSum(s);
            if (lane == 0) ml[j] = s + mfc2_b[j];
        }
    }
    __syncthreads();
    if (tid == 0) {
        float s = 0.f;
        for (int j = 0; j < 36; ++j) s += ml[j];
        mlm_s = s * (1.f / 36.f);
    }
    __syncthreads();

    const float val = valv, plm = plm_s, mlm = mlm_s;
    for (int idx = tid; idx < 1296; idx += 256) {
        int i = idx / 36, j = idx - i * 36;
        q[bg * 1296 + idx] = val + (pl[i] - plm) + (ml[j] - mlm);
    }
}

// ---------------- launch ----------------

extern "C" void kernel_launch(void* const* d_in, const int* in_sizes, int n_in,
                              void* d_out, int out_size, void* d_ws, size_t ws_size,
                              hipStream_t stream)
{
    const float* x       = (const float*)d_in[0];
    const float* conv1_w = (const float*)d_in[1];
    const float* conv1_b = (const float*)d_in[2];
    const float* bn1_g   = (const float*)d_in[3];
    const float* bn1_b   = (const float*)d_in[4];
    const float* bn1_m   = (const float*)d_in[5];
    const float* bn1_v   = (const float*)d_in[6];
    const float* conv2_w = (const float*)d_in[7];
    const float* conv2_b = (const float*)d_in[8];
    const float* bn2_g   = (const float*)d_in[9];
    const float* bn2_b   = (const float*)d_in[10];
    const float* bn2_m   = (const float*)d_in[11];
    const float* bn2_v   = (const float*)d_in[12];
    const float* conv3_w = (const float*)d_in[13];
    const float* conv3_b = (const float*)d_in[14];
    const float* bn3_g   = (const float*)d_in[15];
    const float* bn3_b   = (const float*)d_in[16];
    const float* bn3_m   = (const float*)d_in[17];
    const float* bn3_v   = (const float*)d_in[18];
    const float* pfc1_w  = (const float*)d_in[19];
    const float* pfc1_b  = (const float*)d_in[20];
    const float* pln_g   = (const float*)d_in[21];
    const float* pln_b   = (const float*)d_in[22];
    const float* pfc2_w  = (const float*)d_in[23];
    const float* pfc2_b  = (const float*)d_in[24];
    const float* mfc1_w  = (const float*)d_in[25];
    const float* mfc1_b  = (const float*)d_in[26];
    const float* mln_g   = (const float*)d_in[27];
    const float* mln_b   = (const float*)d_in[28];
    const float* mfc2_w  = (const float*)d_in[29];
    const float* mfc2_b  = (const float*)d_in[30];
    const float* vfc1_w  = (const float*)d_in[31];
    const float* vfc1_b  = (const float*)d_in[32];
    const float* vln_g   = (const float*)d_in[33];
    const float* vln_b   = (const float*)d_in[34];
    const float* vfc2_w  = (const float*)d_in[35];
    const float* vfc2_b  = (const float*)d_in[36];

    const size_t planeW2 = 576 * 128;               // conv2 weight plane elems
    const size_t planeW3 = 1152 * 128;              // conv3 weight plane elems
    const size_t planeBW = (size_t)4608 * 768;      // fc weight plane elems
    const size_t planeA1 = (size_t)CHUNK * 36 * 64; // h1 plane elems (per chunk)
    const size_t planeA2 = (size_t)CHUNK * 36 * 128;// h2/h3 plane elems (per chunk)

    char* ws = (char*)d_ws;
    size_t off = 0;
    auto alloc = [&](size_t bytes) -> char* {
        char* p = ws + off; off += (bytes + 255) & ~(size_t)255; return p;
    };
    __hip_bfloat16* w2t  = (__hip_bfloat16*)alloc(3 * planeW2 * 2);
    __hip_bfloat16* w3t  = (__hip_bfloat16*)alloc(3 * planeW3 * 2);
    __hip_bfloat16* bigw = (__hip_bfloat16*)alloc(3 * planeBW * 2);
    float* selw   = (float*)alloc(36 * 256 * 4);
    float* scale1 = (float*)alloc(64 * 4);
    float* bias1f = (float*)alloc(64 * 4);
    float* scale2 = (float*)alloc(128 * 4);
    float* bias2f = (float*)alloc(128 * 4);
    float* scale3 = (float*)alloc(128 * 4);
    float* bias3f = (float*)alloc(128 * 4);
    float* biasfc = (float*)alloc(768 * 4);
    // ping-pong arenas, per-chunk:
    //   A1: h1 (28.3MB) -> h3 (56.6MB)
    //   A2: h2 (56.6MB) -> fc partials (75.5MB, 12 slots)
    char* A1 = alloc(3 * planeA2 * 2);                    // 56.6 MB
    char* A2 = alloc((size_t)12 * CHUNK * 768 * 4);       // 75.5 MB
    // total ws ~155 MB (round-2 proved >=196 MB available; round-3 crash proved <475)

    prep_scalars_k<<<1, 768, 0, stream>>>(
        conv1_b, bn1_g, bn1_b, bn1_m, bn1_v,
        conv2_b, bn2_g, bn2_b, bn2_m, bn2_v,
        conv3_b, bn3_g, bn3_b, bn3_m, bn3_v,
        pfc1_b, vfc1_b, mfc1_b,
        scale1, bias1f, scale2, bias2f, scale3, bias3f, biasfc);
    prep_convw_k<64><<<288, 256, 0, stream>>>(conv2_w, w2t, planeW2);
    prep_convw_k<128><<<576, 256, 0, stream>>>(conv3_w, w3t, planeW3);
    prep_bigw_k<<<13824, 256, 0, stream>>>(pfc1_w, vfc1_w, mfc1_w, bigw, planeBW);
    prep_selw_k<<<36, 256, 0, stream>>>(mfc1_w, selw);

    __hip_bfloat16* h1s  = (__hip_bfloat16*)A1;
    __hip_bfloat16* h2s  = (__hip_bfloat16*)A2;
    __hip_bfloat16* h3s  = (__hip_bfloat16*)A1;   // overwrites h1s (dead after conv2)
    float*          fpar = (float*)A2;            // overwrites h2s (dead after conv3)

    for (int cchunk = 0; cchunk < NCHUNK; ++cchunk) {
        const int b_base = cchunk * CHUNK;
        conv1_k<<<CHUNK * 36 * 64 / 256, 256, 0, stream>>>(
            x, conv1_w, scale1, bias1f, h1s, planeA1, b_base);
        conv_gemm_k<64><<<CHUNK / 2, 256, 0, stream>>>(
            h1s, planeA1, w2t, planeW2, scale2, bias2f, h2s, planeA2);
        conv_gemm_k<128><<<CHUNK / 2, 256, 0, stream>>>(
            h2s, planeA2, w3t, planeW3, scale3, bias3f, h3s, planeA2);
        fc_partial_k<<<1152, 256, 0, stream>>>(h3s, planeA2, bigw, planeBW, fpar);
        heads_k<<<CHUNK, 256, 0, stream>>>(fpar, biasfc,
            pln_g, pln_b, pfc2_w, pfc2_b,
            mln_g, mln_b, mfc2_w, mfc2_b,
            vln_g, vln_b, vfc2_w, vfc2_b,
            selw, (float*)d_out, b_base);
    }
}

// Round 6
// 1603.181 us; speedup vs baseline: 1.3779x; 1.0589x over previous
//
#include <hip/hip_runtime.h>
#include <hip/hip_bf16.h>

#define BQ 8192
typedef __attribute__((ext_vector_type(8))) __bf16 bf16x8;
typedef __attribute__((ext_vector_type(4))) float f32x4;
typedef __attribute__((ext_vector_type(4))) int int4v;

__device__ __forceinline__ f32x4 mfma16(bf16x8 a, bf16x8 b, f32x4 c) {
    return __builtin_amdgcn_mfma_f32_16x16x32_bf16(a, b, c, 0, 0, 0);
}

// 3-way bf16 split of an fp32 value: v ~= s0+s1+s2 to ~2^-25 rel.
__device__ __forceinline__ void split3(float v, __hip_bfloat16& s0,
                                       __hip_bfloat16& s1, __hip_bfloat16& s2) {
    s0 = __float2bfloat16(v);
    float r = v - __bfloat162float(s0);
    s1 = __float2bfloat16(r);
    r -= __bfloat162float(s1);
    s2 = __float2bfloat16(r);
}

// plane-pair schedule for 6-term fp32-emulated product, grouped by A-plane:
// (a,w) = (0,0),(0,1),(0,2),(1,0),(1,1),(2,0) == A-plane g x W-planes 0..(2-g).
__device__ __forceinline__ int pair_a(int pp) { return (0x211000 >> (4 * pp)) & 0xF; }
__device__ __forceinline__ int pair_w(int pp) { return (0x010210 >> (4 * pp)) & 0xF; }

// ---------------- prep kernels ----------------

__global__ void prep_scalars_k(
    const float* __restrict__ c1b, const float* __restrict__ g1,
    const float* __restrict__ b1,  const float* __restrict__ m1,
    const float* __restrict__ v1,
    const float* __restrict__ c2b, const float* __restrict__ g2,
    const float* __restrict__ b2,  const float* __restrict__ m2,
    const float* __restrict__ v2,
    const float* __restrict__ c3b, const float* __restrict__ g3,
    const float* __restrict__ b3,  const float* __restrict__ m3,
    const float* __restrict__ v3,
    const float* __restrict__ pfb, const float* __restrict__ vfb,
    const float* __restrict__ mfb,
    float* __restrict__ scale1, float* __restrict__ bias1f,
    float* __restrict__ scale2, float* __restrict__ bias2f,
    float* __restrict__ scale3, float* __restrict__ bias3f,
    float* __restrict__ biasfc)
{
    int t = threadIdx.x;  // 768 threads
    if (t < 64) {
        float s = g1[t] * rsqrtf(v1[t] + 1e-5f);
        scale1[t] = s;
        bias1f[t] = (c1b[t] - m1[t]) * s + b1[t];
    }
    if (t < 128) {
        float s2 = g2[t] * rsqrtf(v2[t] + 1e-5f);
        scale2[t] = s2;
        bias2f[t] = (c2b[t] - m2[t]) * s2 + b2[t];
        float s3 = g3[t] * rsqrtf(v3[t] + 1e-5f);
        scale3[t] = s3;
        bias3f[t] = (c3b[t] - m3[t]) * s3 + b3[t];
    }
    if (t < 256)      biasfc[t] = pfb[t];
    else if (t < 512) biasfc[t] = vfb[t - 256];
    else              biasfc[t] = mfb[t - 512];
}

// conv weights (O, CIN, 3, 3) fp32 -> 3 bf16 planes in FRAG-MAJOR layout:
// dest = kt*4096 + (n>>5)*1024 + ((n>>4)&1)*512 + (kk>>3)*128 + (n&15)*8 + (kk&7)
template<int CIN>
__global__ void prep_convw_k(const float* __restrict__ w,
                             __hip_bfloat16* __restrict__ wt, size_t planeW)
{
    int id = blockIdx.x * 256 + threadIdx.x;
    int kk = id & 31;
    int n  = (id >> 5) & 127;
    int kt = id >> 12;
    int k  = kt * 32 + kk;
    int s  = k / CIN;
    int i  = k & (CIN - 1);
    __hip_bfloat16 s0, s1, s2;
    split3(w[(n * CIN + i) * 9 + s], s0, s1, s2);
    size_t dest = (size_t)kt * 4096 + ((n >> 5) * 1024) + (((n >> 4) & 1) * 512)
                + ((kk >> 3) * 128) + ((n & 15) * 8) + (kk & 7);
    wt[dest] = s0; wt[dest + planeW] = s1; wt[dest + 2 * planeW] = s2;
}

// fused FC1 weight -> 3 bf16 planes, frag-major per 128-col group:
// dest = kt*24576 + (n>>7)*4096 + ((n>>6)&1)*2048 + ((n>>4)&3)*512 + (kk>>3)*128 + (n&15)*8 + (kk&7)
// k' = kt*32+kk = p*128+c ; orig k = c*36+p
__global__ void prep_bigw_k(const float* __restrict__ pw,
                            const float* __restrict__ vw,
                            const float* __restrict__ mw,
                            __hip_bfloat16* __restrict__ bigw, size_t planeBW)
{
    int id = blockIdx.x * 256 + threadIdx.x;   // < 4608*768
    int kk = id & 31;
    int n  = (id >> 5) % 768;
    int kt = id / (32 * 768);
    int k2 = kt * 32 + kk;
    int c  = k2 & 127, p = k2 >> 7;
    int k  = c * 36 + p;
    float v;
    if (n < 256)      v = pw[n * 4608 + k];
    else if (n < 512) v = vw[(n - 256) * 4608 + k];
    else              v = mw[(n - 512) * 4644 + k];
    __hip_bfloat16 s0, s1, s2;
    split3(v, s0, s1, s2);
    size_t dest = (size_t)kt * 24576 + ((n >> 7) * 4096) + (((n >> 6) & 1) * 2048)
                + (((n >> 4) & 3) * 512) + ((kk >> 3) * 128) + ((n & 15) * 8) + (kk & 7);
    bigw[dest] = s0; bigw[dest + planeBW] = s1; bigw[dest + 2 * planeBW] = s2;
}

__global__ void prep_selw_k(const float* __restrict__ mw,
                            float* __restrict__ selw)
{
    int j = blockIdx.x, d = threadIdx.x;
    selw[j * 256 + d] = mw[d * 4644 + 4608 + j];
}

// ---------------- conv1 (4->64, K=36): exact fp32 VALU, split-stored ----------------

__global__ __launch_bounds__(256)
void conv1_k(const float* __restrict__ x,               // (B,4,36) full
             const float* __restrict__ w,               // (64,4,9)
             const float* __restrict__ scale, const float* __restrict__ biasf,
             __hip_bfloat16* __restrict__ out, size_t planeA,  // 3 planes (CH,36,64)
             int b_base)
{
    __shared__ float wl[64 * 37];
    int tid = threadIdx.x;
    for (int c = tid; c < 64 * 36; c += 256) {
        int o = c / 36, k = c - o * 36;
        wl[o * 37 + k] = w[c];
    }
    __syncthreads();
    unsigned gid = blockIdx.x * 256 + tid;  // local (chunk) b*36*64 range
    int o = gid & 63;
    unsigned bp = gid >> 6;                 // local b*36+p
    unsigned b = bp / 36;
    int p = bp - b * 36;
    int py = p / 6, px = p - py * 6;
    const float* xb = x + (size_t)(b_base + b) * 4 * 36;
    float acc = 0.f;
#pragma unroll
    for (int i = 0; i < 4; ++i) {
#pragma unroll
        for (int s = 0; s < 9; ++s) {
            int ny = py + s / 3 - 1, nx = px + s % 3 - 1;
            if ((unsigned)ny < 6u && (unsigned)nx < 6u)
                acc += xb[i * 36 + ny * 6 + nx] * wl[o * 37 + i * 9 + s];
        }
    }
    float v = fmaxf(acc * scale[o] + biasf[o], 0.f);
    __hip_bfloat16 s0, s1, s2;
    split3(v, s0, s1, s2);
    size_t idx = (size_t)bp * 64 + o;
    out[idx] = s0; out[idx + planeA] = s1; out[idx + 2 * planeA] = s2;
}

// ---------------- conv2/conv3: implicit-im2col MFMA GEMM, 6-term fp32-emulated ----------------
// 2 images per block (72 rows, 5 row-tiles with half-valid tail). VGPR=64,
// LDS ~19.5KB -> capacity 8 blocks/CU; at CH=4096 the grid (2048) actually
// supplies 8 blocks/CU = 8 waves/SIMD (R6 change is purely grid/chunk-driven).
template<int CIN>
__global__ __launch_bounds__(256, 4)
void conv_gemm_k(const __hip_bfloat16* __restrict__ in, size_t planeA,   // 3 planes (CH,36,CIN)
                 const __hip_bfloat16* __restrict__ wt, size_t planeW,   // 3 planes frag-major [K/32][4096]
                 const float* __restrict__ scale,
                 const float* __restrict__ biasf,
                 __hip_bfloat16* __restrict__ out, size_t planeO)        // 3 planes (CH,36,128)
{
    constexpr int PS  = CIN + 8;
    constexpr int CPB = CIN / 32;
    constexpr int NSLICE = CPB * 9;
    constexpr int XS_ELEMS = 72 * PS;
    __shared__ __align__(16) __hip_bfloat16 smem[XS_ELEMS + CIN];  // xs + zero region
    __hip_bfloat16* xs = smem;

    const int tid  = threadIdx.x;
    const int wave = tid >> 6, lane = tid & 63;
    const int m16  = lane & 15, quad = lane >> 4;
    const int b0   = blockIdx.x * 2;   // local image index (2 images/block)

    if (tid < CIN) smem[XS_ELEMS + tid] = __float2bfloat16(0.f);  // SAME-pad zeros

    f32x4 acc[5][2];
#pragma unroll
    for (int i = 0; i < 5; ++i) { acc[i][0] = f32x4{0,0,0,0}; acc[i][1] = f32x4{0,0,0,0}; }

    const int bo0 = wave * 1024 + lane * 8;          // ct=0 frag (elems)
    const int bo1 = bo0 + 512;                       // ct=1 frag

    constexpr int CHPP = CIN / 8;
    for (int pp = 0; pp < 6; ++pp) {
        const __hip_bfloat16* inb = in + (size_t)pair_a(pp) * planeA + (size_t)b0 * 36 * CIN;
        const __hip_bfloat16* wP  = wt + (size_t)pair_w(pp) * planeW;
        const bool stage_x = (pp == 0) || (pair_a(pp) != pair_a(pp - 1));

        if (stage_x) {   // block-uniform; only 3 of 6 passes
            __syncthreads();   // all waves done reading previous xs (covers zs init at pp=0)
            for (int c = tid; c < 72 * CHPP; c += 256) {
                int pix = c / CHPP;
                int off = (c - pix * CHPP) * 8;
                *(int4v*)(xs + pix * PS + off) = *(const int4v*)(inb + pix * CIN + off);
            }
            __syncthreads();
        }

        // per-pass prologue: load this wave's kt=0 weight frags straight to VGPRs
        bf16x8 wc0 = *(const bf16x8*)(wP + bo0);
        bf16x8 wc1 = *(const bf16x8*)(wP + bo1);

        for (int s = 0; s < 9; ++s) {
            const int dy = s / 3 - 1, dx = s % 3 - 1;
            int aoff[5];
#pragma unroll
            for (int rt = 0; rt < 5; ++rt) {
                int m   = rt * 16 + m16;          // 0..79; valid < 72
                int img = m >= 36;                // 0 or 1 for valid rows
                int p   = m - img * 36;
                int py  = p / 6, px = p - py * 6;
                int ny  = py + dy, nx = px + dx;
                bool ok = (m < 72) && ((unsigned)ny < 6u) && ((unsigned)nx < 6u);
                int base = ok ? ((img * 36 + ny * 6 + nx) * PS) : XS_ELEMS;
                aoff[rt] = base + quad * 8;
            }
#pragma unroll
            for (int c = 0; c < CPB; ++c) {
                const int kt = s * CPB + c;
                const int ktn = (kt + 1 < NSLICE) ? (kt + 1) : 0;
                const __hip_bfloat16* wN = wP + (size_t)ktn * 4096;
                bf16x8 wn0 = *(const bf16x8*)(wN + bo0);
                bf16x8 wn1 = *(const bf16x8*)(wN + bo1);
                const int coff = c * 32;
#pragma unroll
                for (int rt = 0; rt < 5; ++rt) {
                    bf16x8 af = *(const bf16x8*)(smem + aoff[rt] + coff);
                    acc[rt][0] = mfma16(af, wc0, acc[rt][0]);
                    acc[rt][1] = mfma16(af, wc1, acc[rt][1]);
                }
                wc0 = wn0; wc1 = wn1;
            }
        }
    }

    // epilogue: fused BN scale/bias + relu, split-store 3 bf16 planes
#pragma unroll
    for (int ct = 0; ct < 2; ++ct) {
        const int n = wave * 32 + ct * 16 + m16;
        const float sc = scale[n], bi = biasf[n];
#pragma unroll
        for (int rt = 0; rt < 5; ++rt) {
            const int mrow = rt * 16 + quad * 4;
            if (mrow < 72) {
#pragma unroll
                for (int r = 0; r < 4; ++r) {
                    float v = fmaxf(acc[rt][ct][r] * sc + bi, 0.f);
                    __hip_bfloat16 s0, s1, s2;
                    split3(v, s0, s1, s2);
                    size_t idx = (size_t)(b0 * 36 + mrow + r) * 128 + n;
                    out[idx] = s0; out[idx + planeO] = s1; out[idx + 2 * planeO] = s2;
                }
            }
        }
    }
}

// ---------------- FC1 partial GEMM: A-plane grouped, runtime K-split ----------------
// All NS partial slots are summed in heads_k, so a block accumulates several
// plane-pairs into ONE acc. g0 = A0 x {W0,W1,W2}, g1 = A1 x {W0,W1}, g2 = A2 x {W0}.
// Work balanced by K-split inversely to NW. CH=2048: NS=12 (NKT 24/36/72);
// CH=4096: NS=6 (NKT 48/72/144). Grid = (CH/128) x 6 x NS = 1152 in both.

template<int NW>
__device__ __forceinline__ void fc_body(
    const __hip_bfloat16* __restrict__ Ap,    // A-plane base (g applied)
    const __hip_bfloat16* __restrict__ Bp,    // Bw + nblk*4096 (W-plane 0)
    size_t planeBW, int kt0, int NKT,
    float* __restrict__ outp, size_t m0,
    __hip_bfloat16* smem, int tid, int wave, int lane)
{
    constexpr int ABUF = 4096;
    const int NPH = NW * NKT;
    const int m16 = lane & 15, quad = lane >> 4;
    const int wr = wave >> 1, wc = wave & 1;
    const int cr = tid >> 2, co = (tid & 3) * 8;

    f32x4 acc[4][4];
#pragma unroll
    for (int i = 0; i < 4; ++i)
#pragma unroll
        for (int j = 0; j < 4; ++j) acc[i][j] = f32x4{0,0,0,0};

    int ao[4];
#pragma unroll
    for (int i = 0; i < 4; ++i) ao[i] = wr * 2048 + i * 512 + lane * 8;
    const int bofs = wc * 2048 + lane * 8;
    const int adst = ((cr >> 4) & 3) * 512 + (tid & 3) * 128 + (cr & 15) * 8;

    auto ldA = [&](int ktr, int4v& a0, int4v& a1) {   // ktr relative to kt0
        const __hip_bfloat16* base = Ap + (m0 + cr) * 4608 + (kt0 + ktr) * 32 + co;
        a0 = *(const int4v*)base;
        a1 = *(const int4v*)(base + (size_t)64 * 4608);
    };
    auto ldB = [&](int p, bf16x8* bf) {               // phase p -> (ktr, w)
        const int ktr = p / NW, w = p - ktr * NW;
        const __hip_bfloat16* base = Bp + (size_t)w * planeBW
                                   + (size_t)(kt0 + ktr) * 24576 + bofs;
#pragma unroll
        for (int i = 0; i < 4; ++i) bf[i] = *(const bf16x8*)(base + i * 512);
    };
    auto stA = [&](int buf, int4v a0, int4v a1) {
        __hip_bfloat16* base = smem + buf * ABUF;
        *(int4v*)(base + adst) = a0;                  // rows 0..63
        *(int4v*)(base + 2048 + adst) = a1;           // rows 64..127
    };

    // prologue
    int4v pa0, pa1, qa0, qa1;
    bf16x8 Bc[4], B1[4], Bn[4];
    {
        int4v a0, a1;
        ldA(0, a0, a1);
        ldB(0, Bc);
        ldA(1, pa0, pa1);
        if (NPH > 1) ldB(1, B1);
        stA(0, a0, a1);
    }
    __syncthreads();
    int cur = 0;

#pragma unroll 2
    for (int ktr = 0; ktr < NKT; ++ktr) {
        // A prefetch, 2-kt slack
        { int ktn = (ktr + 2 < NKT) ? (ktr + 2) : 0; ldA(ktn, qa0, qa1); }
        // A fragments for this kt, shared across all NW B-phases
        const __hip_bfloat16* base = smem + cur * ABUF;
        bf16x8 af[4];
#pragma unroll
        for (int i = 0; i < 4; ++i) af[i] = *(const bf16x8*)(base + ao[i]);
#pragma unroll
        for (int w = 0; w < NW; ++w) {
            int p2 = ktr * NW + w + 2;
            if (p2 >= NPH) p2 = 0;                    // clamp: harmless, in-bounds
            ldB(p2, Bn);
#pragma unroll
            for (int i = 0; i < 4; ++i)
#pragma unroll
                for (int j = 0; j < 4; ++j)
                    acc[i][j] = mfma16(af[i], Bc[j], acc[i][j]);
#pragma unroll
            for (int i = 0; i < 4; ++i) { Bc[i] = B1[i]; B1[i] = Bn[i]; }
        }
        if (ktr + 1 < NKT) stA(cur ^ 1, pa0, pa1);    // waits loads issued last kt
        __syncthreads();
        cur ^= 1;
        pa0 = qa0; pa1 = qa1;
    }

#pragma unroll
    for (int i = 0; i < 4; ++i) {
        const int row = wr * 64 + i * 16 + quad * 4;
#pragma unroll
        for (int j = 0; j < 4; ++j) {
            const int col = wc * 64 + j * 16 + m16;
#pragma unroll
            for (int r = 0; r < 4; ++r)
                outp[(m0 + row + r) * 768 + col] = acc[i][j][r];
        }
    }
}

__global__ __launch_bounds__(256, 3)
void fc_partial_k(const __hip_bfloat16* __restrict__ A, size_t planeF,    // 3 planes (CH,4608)
                  const __hip_bfloat16* __restrict__ Bw, size_t planeBW,  // 3 planes frag-major [144][24576]
                  float* __restrict__ partial,                            // [NS](CH,768)
                  int chunk, int big)
{
    constexpr int ABUF = 4096;
    __shared__ __align__(16) __hip_bfloat16 smem[2 * ABUF];   // 16 KB
    const int tid = threadIdx.x, wave = tid >> 6, lane = tid & 63;
    const int nmblk = chunk >> 7;
    const int mblk = blockIdx.x & (nmblk - 1);
    int rest = blockIdx.x / nmblk;
    const int nblk = rest % 6;
    const int slot = rest / 6;
    const size_t m0 = (size_t)mblk * 128;

    const __hip_bfloat16* Bp = Bw + (size_t)nblk * 4096;
    float* outp = partial + (size_t)slot * chunk * 768 + (size_t)nblk * 128;

    if (big) {   // NS=6: g0 slots 0-2 (NKT 48), g1 slots 3-4 (72), g2 slot 5 (144)
        if (slot < 3)
            fc_body<3>(A, Bp, planeBW, slot * 48, 48, outp, m0, smem, tid, wave, lane);
        else if (slot < 5)
            fc_body<2>(A + planeF, Bp, planeBW, (slot - 3) * 72, 72, outp, m0, smem, tid, wave, lane);
        else
            fc_body<1>(A + 2 * planeF, Bp, planeBW, 0, 144, outp, m0, smem, tid, wave, lane);
    } else {     // NS=12: g0 slots 0-5 (24), g1 slots 6-9 (36), g2 slots 10-11 (72)
        if (slot < 6)
            fc_body<3>(A, Bp, planeBW, slot * 24, 24, outp, m0, smem, tid, wave, lane);
        else if (slot < 10)
            fc_body<2>(A + planeF, Bp, planeBW, (slot - 6) * 36, 36, outp, m0, smem, tid, wave, lane);
        else
            fc_body<1>(A + 2 * planeF, Bp, planeBW, (slot - 10) * 72, 72, outp, m0, smem, tid, wave, lane);
    }
}

// ---------------- heads: partial-sum + LN + small GEMVs + argmax + dueling (fp32) ----------------

__global__ __launch_bounds__(256)
void heads_k(const float* __restrict__ partial,          // [ns](CH,768): [piece|value|move]
             const float* __restrict__ biasfc,           // 768
             const float* __restrict__ pln_g, const float* __restrict__ pln_b,
             const float* __restrict__ pfc2_w, const float* __restrict__ pfc2_b,
             const float* __restrict__ mln_g, const float* __restrict__ mln_b,
             const float* __restrict__ mfc2_w, const float* __restrict__ mfc2_b,
             const float* __restrict__ vln_g, const float* __restrict__ vln_b,
             const float* __restrict__ vfc2_w, const float* __restrict__ vfc2_b,
             const float* __restrict__ selw,             // (36,256)
             float* __restrict__ q,                      // (B,1296) full
             int b_base, int ns, int chunk)
{
    __shared__ float hp[256], hv[256], hm[256];
    __shared__ float pl[36], ml[36];
    __shared__ float red[4];
    __shared__ float valv, plm_s, mlm_s;
    __shared__ int amax_s;

    const int tid = threadIdx.x, wave = tid >> 6, lane = tid & 63;
    const size_t b = blockIdx.x;                // local
    const size_t bg = b_base + b;               // global

    // inline fc-reduce: sum ns partials + bias
    float pp = biasfc[tid], vv = biasfc[256 + tid], mm = biasfc[512 + tid];
    for (int k = 0; k < ns; ++k) {
        const float* row = partial + (size_t)k * chunk * 768 + b * 768;
        pp += row[tid]; vv += row[256 + tid]; mm += row[512 + tid];
    }

    auto warpSum = [&](float v) {
        v += __shfl_xor(v, 1);  v += __shfl_xor(v, 2);  v += __shfl_xor(v, 4);
        v += __shfl_xor(v, 8);  v += __shfl_xor(v, 16); v += __shfl_xor(v, 32);
        return v;
    };
    auto blockSum = [&](float v) {
        v = warpSum(v);
        if (lane == 0) red[wave] = v;
        __syncthreads();
        float s = red[0] + red[1] + red[2] + red[3];
        __syncthreads();
        return s;
    };
    auto lnrelu = [&](float x, const float* g, const float* bb) {
        float mu  = blockSum(x) * (1.f / 256.f);
        float d   = x - mu;
        float var = blockSum(d * d) * (1.f / 256.f);
        float y   = d * rsqrtf(var + 1e-5f) * g[tid] + bb[tid];
        return fmaxf(y, 0.f);
    };

    hp[tid] = lnrelu(pp, pln_g, pln_b);
    hv[tid] = lnrelu(vv, vln_g, vln_b);
    __syncthreads();

    {
        float h0 = hp[lane], h1 = hp[64 + lane], h2 = hp[128 + lane], h3 = hp[192 + lane];
#pragma unroll
        for (int jj = 0; jj < 9; ++jj) {
            int j = wave * 9 + jj;
            const float* wr_ = pfc2_w + j * 256;
            float s = h0 * wr_[lane] + h1 * wr_[64 + lane]
                    + h2 * wr_[128 + lane] + h3 * wr_[192 + lane];
            s = warpSum(s);
            if (lane == 0) pl[j] = s + pfc2_b[j];
        }
        if (wave == 0) {
            float g0 = hv[lane], g1 = hv[64 + lane], g2 = hv[128 + lane], g3 = hv[192 + lane];
            float s = g0 * vfc2_w[lane] + g1 * vfc2_w[64 + lane]
                    + g2 * vfc2_w[128 + lane] + g3 * vfc2_w[192 + lane];
            s = warpSum(s);
            if (lane == 0) valv = s + vfc2_b[0];
        }
    }
    __syncthreads();
    if (tid == 0) {   // first-max argmax (jnp semantics) + mean
        float m = -1e30f, s = 0.f; int idx = 0;
        for (int j = 0; j < 36; ++j) { float v = pl[j]; s += v; if (v > m) { m = v; idx = j; } }
        plm_s = s * (1.f / 36.f); amax_s = idx;
    }
    __syncthreads();

    mm += selw[amax_s * 256 + tid];   // one-hot concat == single column add
    hm[tid] = lnrelu(mm, mln_g, mln_b);
    __syncthreads();
    {
        float h0 = hm[lane], h1 = hm[64 + lane], h2 = hm[128 + lane], h3 = hm[192 + lane];
#pragma unroll
        for (int jj = 0; jj < 9; ++jj) {
            int j = wave * 9 + jj;
            const float* wr_ = mfc2_w + j * 256;
            float s = h0 * wr_[lane] + h1 * wr_[64 + lane]
                    + h2 * wr_[128 + lane] + h3 * wr_[192 + lane];
            s = warpSum(s);
            if (lane == 0) ml[j] = s + mfc2_b[j];
        }
    }
    __syncthreads();
    if (tid == 0) {
        float s = 0.f;
        for (int j = 0; j < 36; ++j) s += ml[j];
        mlm_s = s * (1.f / 36.f);
    }
    __syncthreads();

    const float val = valv, plm = plm_s, mlm = mlm_s;
    for (int idx = tid; idx < 1296; idx += 256) {
        int i = idx / 36, j = idx - i * 36;
        q[bg * 1296 + idx] = val + (pl[i] - plm) + (ml[j] - mlm);
    }
}

// ---------------- launch ----------------

extern "C" void kernel_launch(void* const* d_in, const int* in_sizes, int n_in,
                              void* d_out, int out_size, void* d_ws, size_t ws_size,
                              hipStream_t stream)
{
    const float* x       = (const float*)d_in[0];
    const float* conv1_w = (const float*)d_in[1];
    const float* conv1_b = (const float*)d_in[2];
    const float* bn1_g   = (const float*)d_in[3];
    const float* bn1_b   = (const float*)d_in[4];
    const float* bn1_m   = (const float*)d_in[5];
    const float* bn1_v   = (const float*)d_in[6];
    const float* conv2_w = (const float*)d_in[7];
    const float* conv2_b = (const float*)d_in[8];
    const float* bn2_g   = (const float*)d_in[9];
    const float* bn2_b   = (const float*)d_in[10];
    const float* bn2_m   = (const float*)d_in[11];
    const float* bn2_v   = (const float*)d_in[12];
    const float* conv3_w = (const float*)d_in[13];
    const float* conv3_b = (const float*)d_in[14];
    const float* bn3_g   = (const float*)d_in[15];
    const float* bn3_b   = (const float*)d_in[16];
    const float* bn3_m   = (const float*)d_in[17];
    const float* bn3_v   = (const float*)d_in[18];
    const float* pfc1_w  = (const float*)d_in[19];
    const float* pfc1_b  = (const float*)d_in[20];
    const float* pln_g   = (const float*)d_in[21];
    const float* pln_b   = (const float*)d_in[22];
    const float* pfc2_w  = (const float*)d_in[23];
    const float* pfc2_b  = (const float*)d_in[24];
    const float* mfc1_w  = (const float*)d_in[25];
    const float* mfc1_b  = (const float*)d_in[26];
    const float* mln_g   = (const float*)d_in[27];
    const float* mln_b   = (const float*)d_in[28];
    const float* mfc2_w  = (const float*)d_in[29];
    const float* mfc2_b  = (const float*)d_in[30];
    const float* vfc1_w  = (const float*)d_in[31];
    const float* vfc1_b  = (const float*)d_in[32];
    const float* vln_g   = (const float*)d_in[33];
    const float* vln_b   = (const float*)d_in[34];
    const float* vfc2_w  = (const float*)d_in[35];
    const float* vfc2_b  = (const float*)d_in[36];

    const size_t planeW2 = 576 * 128;               // conv2 weight plane elems
    const size_t planeW3 = 1152 * 128;              // conv3 weight plane elems
    const size_t planeBW = (size_t)4608 * 768;      // fc weight plane elems

    // workspace layout size for a given (chunk, n_slots)
    auto layout_total = [&](int CH, int NS) -> size_t {
        size_t t = 0;
        auto add = [&](size_t b) { t += (b + 255) & ~(size_t)255; };
        add(3 * planeW2 * 2); add(3 * planeW3 * 2); add(3 * planeBW * 2);
        add(36 * 256 * 4);
        add(64 * 4); add(64 * 4); add(128 * 4); add(128 * 4);
        add(128 * 4); add(128 * 4); add(768 * 4);
        size_t pA2 = (size_t)CH * 36 * 128;
        add(3 * pA2 * 2);                                      // A1
        size_t par = (size_t)NS * CH * 768 * 4;
        add((3 * pA2 * 2 > par) ? 3 * pA2 * 2 : par);          // A2
        return t;
    };

    // Runtime chunk selection: big path (CH=4096, 6 fc slots) needs ~249 MB;
    // fall back to the proven CH=2048 / 12-slot config otherwise.
    const int big = (layout_total(4096, 6) <= ws_size) ? 1 : 0;
    const int CH  = big ? 4096 : 2048;
    const int NS  = big ? 6 : 12;
    const int NCH = BQ / CH;

    const size_t planeA1 = (size_t)CH * 36 * 64;
    const size_t planeA2 = (size_t)CH * 36 * 128;

    char* ws = (char*)d_ws;
    size_t off = 0;
    auto alloc = [&](size_t bytes) -> char* {
        char* p = ws + off; off += (bytes + 255) & ~(size_t)255; return p;
    };
    __hip_bfloat16* w2t  = (__hip_bfloat16*)alloc(3 * planeW2 * 2);
    __hip_bfloat16* w3t  = (__hip_bfloat16*)alloc(3 * planeW3 * 2);
    __hip_bfloat16* bigw = (__hip_bfloat16*)alloc(3 * planeBW * 2);
    float* selw   = (float*)alloc(36 * 256 * 4);
    float* scale1 = (float*)alloc(64 * 4);
    float* bias1f = (float*)alloc(64 * 4);
    float* scale2 = (float*)alloc(128 * 4);
    float* bias2f = (float*)alloc(128 * 4);
    float* scale3 = (float*)alloc(128 * 4);
    float* bias3f = (float*)alloc(128 * 4);
    float* biasfc = (float*)alloc(768 * 4);
    // ping-pong arenas, per-chunk: A1: h1 -> h3 ; A2: h2 -> fc partials
    size_t parBytes = (size_t)NS * CH * 768 * 4;
    char* A1 = alloc(3 * planeA2 * 2);
    char* A2 = alloc((3 * planeA2 * 2 > parBytes) ? 3 * planeA2 * 2 : parBytes);

    prep_scalars_k<<<1, 768, 0, stream>>>(
        conv1_b, bn1_g, bn1_b, bn1_m, bn1_v,
        conv2_b, bn2_g, bn2_b, bn2_m, bn2_v,
        conv3_b, bn3_g, bn3_b, bn3_m, bn3_v,
        pfc1_b, vfc1_b, mfc1_b,
        scale1, bias1f, scale2, bias2f, scale3, bias3f, biasfc);
    prep_convw_k<64><<<288, 256, 0, stream>>>(conv2_w, w2t, planeW2);
    prep_convw_k<128><<<576, 256, 0, stream>>>(conv3_w, w3t, planeW3);
    prep_bigw_k<<<13824, 256, 0, stream>>>(pfc1_w, vfc1_w, mfc1_w, bigw, planeBW);
    prep_selw_k<<<36, 256, 0, stream>>>(mfc1_w, selw);

    __hip_bfloat16* h1s  = (__hip_bfloat16*)A1;
    __hip_bfloat16* h2s  = (__hip_bfloat16*)A2;
    __hip_bfloat16* h3s  = (__hip_bfloat16*)A1;   // overwrites h1s (dead after conv2)
    float*          fpar = (float*)A2;            // overwrites h2s (dead after conv3)

    for (int cchunk = 0; cchunk < NCH; ++cchunk) {
        const int b_base = cchunk * CH;
        conv1_k<<<CH * 9, 256, 0, stream>>>(
            x, conv1_w, scale1, bias1f, h1s, planeA1, b_base);
        conv_gemm_k<64><<<CH / 2, 256, 0, stream>>>(
            h1s, planeA1, w2t, planeW2, scale2, bias2f, h2s, planeA2);
        conv_gemm_k<128><<<CH / 2, 256, 0, stream>>>(
            h2s, planeA2, w3t, planeW3, scale3, bias3f, h3s, planeA2);
        fc_partial_k<<<(CH / 128) * 6 * NS / (big ? 2 : 1) * (big ? 2 : 1), 256, 0, stream>>>(
            h3s, planeA2, bigw, planeBW, fpar, CH, big);
        heads_k<<<CH, 256, 0, stream>>>(fpar, biasfc,
            pln_g, pln_b, pfc2_w, pfc2_b,
            mln_g, mln_b, mfc2_w, mfc2_b,
            vln_g, vln_b, vfc2_w, vfc2_b,
            selw, (float*)d_out, b_base, NS, CH);
    }
}